// Round 2
// baseline (30655.692 us; speedup 1.0000x reference)
//
#include <hip/hip_runtime.h>
#include <hip/hip_bf16.h>

#define B_   64
#define S_   1024
#define I_   512
#define H_   512
#define G4   2048   // 4*H
#define KTOT 1024   // I_ + H_
#define NBLK 32     // persistent grid (<< 256 CUs -> co-resident)

typedef float f32x4 __attribute__((ext_vector_type(4)));
typedef short s16x8 __attribute__((ext_vector_type(8)));

__device__ inline ushort f2bf(float f) {
    union { __hip_bfloat16 h; ushort u; } v;
    v.h = __float2bfloat16(f);
    return v.u;
}

__device__ inline s16x8 cvt_frag(const float* p) {
    float4 a = *(const float4*)p;
    float4 b = *(const float4*)(p + 4);
    s16x8 r;
    r[0] = (short)f2bf(a.x); r[1] = (short)f2bf(a.y);
    r[2] = (short)f2bf(a.z); r[3] = (short)f2bf(a.w);
    r[4] = (short)f2bf(b.x); r[5] = (short)f2bf(b.y);
    r[6] = (short)f2bf(b.z); r[7] = (short)f2bf(b.w);
    return r;
}

// WUt[g][k] = (k<512 ? W[k][g] : U[k-512][g]) as bf16.  [2048][1024]
__global__ __launch_bounds__(1024) void prep_wut(const float* __restrict__ W,
                                                 const float* __restrict__ U,
                                                 ushort* __restrict__ WUt) {
    __shared__ ushort lds[32][33];
    int g0 = blockIdx.x * 32, k0 = blockIdx.y * 32;
    int tx = threadIdx.x, ty = threadIdx.y;
    int k = k0 + ty, g = g0 + tx;
    float v = (k < I_) ? W[(size_t)k * G4 + g] : U[(size_t)(k - I_) * G4 + g];
    lds[ty][tx] = f2bf(v);
    __syncthreads();
    WUt[(size_t)(g0 + ty) * KTOT + k0 + tx] = lds[tx][ty];
}

__global__ __launch_bounds__(256) void init_all(ushort* __restrict__ h0,
                                                ushort* __restrict__ h1,
                                                float* __restrict__ cg,
                                                int* __restrict__ flags) {
    int i = blockIdx.x * 256 + threadIdx.x;   // 32768 total
    h0[i] = 0;
    h1[i] = 0;
    cg[i] = 0.0f;
    if (i < NBLK) flags[i] = 0;
}

// Persistent recurrent kernel: 32 blocks, block bid owns hidden cols
// [bid*16,+16) for all 4 gates (64 gate-cols), all 64 batch rows.
// Per step: x@W computed BEFORE the flag wait (h-independent, masks skew),
// U-slice lives in 128 VGPRs, W-slice streamed from L2 (off critical path).
// One agent-scope flag barrier per step; h double-buffered by parity.
// Spin is budget-bounded: on wedge, kernel terminates (wrong data, no hang).
__global__ __launch_bounds__(256, 1) void lstm_persist(
    const float* __restrict__ x, const ushort* __restrict__ WUt,
    const float* __restrict__ bias,
    ushort* __restrict__ h0buf, ushort* __restrict__ h1buf,
    float* __restrict__ cg, int* __restrict__ flags,
    float* __restrict__ out)
{
    __shared__ float glt[64][68];   // [gatecol][batch] transposed gate staging
    __shared__ float clds[64][16];  // cell state, block-resident all 1024 steps

    int bid = blockIdx.x;
    int tid = threadIdx.x;
    int wid = tid >> 6, lane = tid & 63;
    int wr = wid >> 1, wc = wid & 1;          // wave = [32 batch, 32 gatecol]
    int m = lane & 15, q = lane >> 4;

    // gate-col c = wc*32 + ct*16 + m  ->  WUt row = (wc*2+ct)*H_ + bid*16 + m
    const ushort* wrow[2];
    s16x8 bU[2][16];                           // persistent U-slice: 128 VGPRs
    #pragma unroll
    for (int ct = 0; ct < 2; ++ct) {
        const ushort* bp = WUt + (size_t)((wc * 2 + ct) * H_ + bid * 16 + m) * KTOT + q * 8;
        wrow[ct] = bp;                         // W part (k in [0,512))
        #pragma unroll
        for (int kk = 0; kk < 16; ++kk)
            bU[ct][kk] = *(const s16x8*)(bp + 512 + kk * 32);
    }

    // pointwise role: thread -> (batch pb, 4 hidden cols at pj)
    int pb = tid >> 2, pj = (tid & 3) << 2;
    *(f32x4*)&clds[pb][pj] = *(const f32x4*)(cg + (size_t)pb * H_ + bid * 16 + pj);
    f32x4 bgate[4];
    #pragma unroll
    for (int g = 0; g < 4; ++g)
        bgate[g] = *(const f32x4*)(bias + g * H_ + bid * 16 + pj);
    __syncthreads();

    const float* xr0base = x + (size_t)(wr * 32 + m) * S_ * I_ + q * 8;
    const float* xr1base = x + (size_t)(wr * 32 + 16 + m) * S_ * I_ + q * 8;

    int budget = 4 << 20;   // ~4M polls total: wedge -> fast termination, no GPU hang

    for (int ts = 0; ts < S_; ++ts) {
        // 1. x@W for this step (no h dependency; overlaps other blocks' step ts-1)
        const float* xr0 = xr0base + (size_t)ts * I_;
        const float* xr1 = xr1base + (size_t)ts * I_;
        f32x4 acc[2][2] = {};
        #pragma unroll
        for (int kk = 0; kk < 16; ++kk) {
            s16x8 A0 = cvt_frag(xr0 + kk * 32);
            s16x8 A1 = cvt_frag(xr1 + kk * 32);
            s16x8 B0 = *(const s16x8*)(wrow[0] + kk * 32);
            s16x8 B1 = *(const s16x8*)(wrow[1] + kk * 32);
            acc[0][0] = __builtin_amdgcn_mfma_f32_16x16x32_bf16(A0, B0, acc[0][0], 0, 0, 0);
            acc[0][1] = __builtin_amdgcn_mfma_f32_16x16x32_bf16(A0, B1, acc[0][1], 0, 0, 0);
            acc[1][0] = __builtin_amdgcn_mfma_f32_16x16x32_bf16(A1, B0, acc[1][0], 0, 0, 0);
            acc[1][1] = __builtin_amdgcn_mfma_f32_16x16x32_bf16(A1, B1, acc[1][1], 0, 0, 0);
        }

        // 2. wait until every block published h_ts (flag >= ts)
        if (tid < NBLK) {
            while (budget > 0 &&
                   __hip_atomic_load(&flags[tid], __ATOMIC_ACQUIRE,
                                     __HIP_MEMORY_SCOPE_AGENT) < ts) {
                __builtin_amdgcn_s_sleep(2);
                --budget;
            }
        }
        __syncthreads();
        __builtin_amdgcn_fence(__ATOMIC_ACQUIRE, "agent");

        // 3. h @ U-slice (A from h buffer, B from VGPRs) accumulated on top
        const ushort* hrow = (ts & 1) ? h1buf : h0buf;
        const ushort* ha0 = hrow + (size_t)(wr * 32 + m) * H_ + q * 8;
        const ushort* ha1 = hrow + (size_t)(wr * 32 + 16 + m) * H_ + q * 8;
        #pragma unroll
        for (int kk = 0; kk < 16; ++kk) {
            s16x8 A0 = *(const s16x8*)(ha0 + kk * 32);
            s16x8 A1 = *(const s16x8*)(ha1 + kk * 32);
            acc[0][0] = __builtin_amdgcn_mfma_f32_16x16x32_bf16(A0, bU[0][kk], acc[0][0], 0, 0, 0);
            acc[0][1] = __builtin_amdgcn_mfma_f32_16x16x32_bf16(A0, bU[1][kk], acc[0][1], 0, 0, 0);
            acc[1][0] = __builtin_amdgcn_mfma_f32_16x16x32_bf16(A1, bU[0][kk], acc[1][0], 0, 0, 0);
            acc[1][1] = __builtin_amdgcn_mfma_f32_16x16x32_bf16(A1, bU[1][kk], acc[1][1], 0, 0, 0);
        }

        // 4. stage gates transposed: glt[gatecol][batch]
        #pragma unroll
        for (int bt = 0; bt < 2; ++bt)
            #pragma unroll
            for (int ct = 0; ct < 2; ++ct)
                *(f32x4*)&glt[wc * 32 + ct * 16 + m][wr * 32 + bt * 16 + q * 4] = acc[bt][ct];
        __syncthreads();

        // 5. pointwise: gates -> c,h  (c stays in LDS)
        float hv4[4], cv4[4];
        #pragma unroll
        for (int jj = 0; jj < 4; ++jj) {
            int jl = pj + jj;
            float gi = glt[jl][pb]      + bgate[0][jj];
            float gf = glt[16 + jl][pb] + bgate[1][jj];
            float gg = glt[32 + jl][pb] + bgate[2][jj];
            float go = glt[48 + jl][pb] + bgate[3][jj];
            float iv = 1.f / (1.f + __expf(-gi));
            float fv = 1.f / (1.f + __expf(-gf));
            float gv = tanhf(gg);
            float ov = 1.f / (1.f + __expf(-go));
            float cv = fv * clds[pb][jl] + iv * gv;
            clds[pb][jl] = cv;
            float hv = ov * tanhf(cv);
            hv4[jj] = hv; cv4[jj] = cv;
        }
        // publish h_{ts+1} slice (bf16, 8B store)
        ushort4 hsv;
        hsv.x = f2bf(hv4[0]); hsv.y = f2bf(hv4[1]);
        hsv.z = f2bf(hv4[2]); hsv.w = f2bf(hv4[3]);
        ushort* hnext = ((ts + 1) & 1) ? h1buf : h0buf;
        *(ushort4*)(hnext + (size_t)pb * H_ + bid * 16 + pj) = hsv;

        // 6. release h writes, then signal
        __builtin_amdgcn_fence(__ATOMIC_RELEASE, "agent");
        __syncthreads();
        if (tid == 0)
            __hip_atomic_store(&flags[bid], ts + 1, __ATOMIC_RELEASE,
                               __HIP_MEMORY_SCOPE_AGENT);

        // 7. deferred (off critical path): hidden_seq / final h_t,c_t stores
        f32x4 hvv = {hv4[0], hv4[1], hv4[2], hv4[3]};
        *(f32x4*)(out + ((size_t)pb * S_ + ts) * H_ + bid * 16 + pj) = hvv;
        if (ts == S_ - 1) {
            f32x4 cvv = {cv4[0], cv4[1], cv4[2], cv4[3]};
            size_t tail = (size_t)B_ * S_ * H_;
            *(f32x4*)(out + tail + (size_t)pb * H_ + bid * 16 + pj) = hvv;
            *(f32x4*)(out + tail + (size_t)B_ * H_ + (size_t)pb * H_ + bid * 16 + pj) = cvv;
        }
    }

    // persist cell state (graph-replay safe: init_all re-zeros each run)
    __syncthreads();
    *(f32x4*)(cg + (size_t)pb * H_ + bid * 16 + pj) = *(const f32x4*)&clds[pb][pj];
}

extern "C" void kernel_launch(void* const* d_in, const int* in_sizes, int n_in,
                              void* d_out, int out_size, void* d_ws, size_t ws_size,
                              hipStream_t stream) {
    const float* x    = (const float*)d_in[0];
    const float* W    = (const float*)d_in[1];
    const float* U    = (const float*)d_in[2];
    const float* bias = (const float*)d_in[3];
    float* out = (float*)d_out;
    char* ws = (char*)d_ws;

    // ws layout (~4.46 MiB, same footprint as the previously-passing kernel):
    // WUt 4MiB | h0 64K | h1 64K | c 128K | flags 4K
    ushort* WUt = (ushort*)ws;
    size_t off = (size_t)4 * 1024 * 1024;
    ushort* h0 = (ushort*)(ws + off); off += (size_t)B_ * H_ * sizeof(ushort);
    ushort* h1 = (ushort*)(ws + off); off += (size_t)B_ * H_ * sizeof(ushort);
    float*  cg = (float*)(ws + off);  off += (size_t)B_ * H_ * sizeof(float);
    int* flags = (int*)(ws + off);

    prep_wut<<<dim3(G4 / 32, KTOT / 32), dim3(32, 32), 0, stream>>>(W, U, WUt);
    init_all<<<(B_ * H_) / 256, 256, 0, stream>>>(h0, h1, cg, flags);
    lstm_persist<<<dim3(NBLK), 256, 0, stream>>>(x, WUt, bias, h0, h1, cg,
                                                 flags, out);
}

// Round 3
// 26656.729 us; speedup vs baseline: 1.1500x; 1.1500x over previous
//
#include <hip/hip_runtime.h>
#include <hip/hip_bf16.h>

#define B_   64
#define S_   1024
#define I_   512
#define H_   512
#define G4   2048   // 4*H
#define KTOT 1024   // I_ + H_
#define NBLK 32     // persistent grid (<< 256 CUs -> co-resident)

typedef float f32x4 __attribute__((ext_vector_type(4)));
typedef short s16x8 __attribute__((ext_vector_type(8)));

__device__ inline ushort f2bf(float f) {
    union { __hip_bfloat16 h; ushort u; } v;
    v.h = __float2bfloat16(f);
    return v.u;
}

__device__ inline s16x8 cvt_frag(const float* p) {
    float4 a = *(const float4*)p;
    float4 b = *(const float4*)(p + 4);
    s16x8 r;
    r[0] = (short)f2bf(a.x); r[1] = (short)f2bf(a.y);
    r[2] = (short)f2bf(a.z); r[3] = (short)f2bf(a.w);
    r[4] = (short)f2bf(b.x); r[5] = (short)f2bf(b.y);
    r[6] = (short)f2bf(b.z); r[7] = (short)f2bf(b.w);
    return r;
}

// Coherent (agent-scope, cache-bypassing) 16B h-frag load as 2x8B relaxed
// atomics. RELAXED (not acquire!) -> sc0/sc1 bits only, NO buffer_inv.
__device__ inline s16x8 ld_h16(const ushort* p) {
    union { unsigned long long u[2]; s16x8 v; } r;
    const unsigned long long* q = (const unsigned long long*)p;
    r.u[0] = __hip_atomic_load(q,     __ATOMIC_RELAXED, __HIP_MEMORY_SCOPE_AGENT);
    r.u[1] = __hip_atomic_load(q + 1, __ATOMIC_RELAXED, __HIP_MEMORY_SCOPE_AGENT);
    return r.v;
}

// WUt[g][k] = (k<512 ? W[k][g] : U[k-512][g]) as bf16.  [2048][1024]
__global__ __launch_bounds__(1024) void prep_wut(const float* __restrict__ W,
                                                 const float* __restrict__ U,
                                                 ushort* __restrict__ WUt) {
    __shared__ ushort lds[32][33];
    int g0 = blockIdx.x * 32, k0 = blockIdx.y * 32;
    int tx = threadIdx.x, ty = threadIdx.y;
    int k = k0 + ty, g = g0 + tx;
    float v = (k < I_) ? W[(size_t)k * G4 + g] : U[(size_t)(k - I_) * G4 + g];
    lds[ty][tx] = f2bf(v);
    __syncthreads();
    WUt[(size_t)(g0 + ty) * KTOT + k0 + tx] = lds[tx][ty];
}

__global__ __launch_bounds__(256) void init_all(ushort* __restrict__ h0,
                                                ushort* __restrict__ h1,
                                                float* __restrict__ cg,
                                                int* __restrict__ flags) {
    int i = blockIdx.x * 256 + threadIdx.x;   // 32768 total
    h0[i] = 0;
    h1[i] = 0;
    cg[i] = 0.0f;
    if (i < NBLK) flags[i] = 0;
}

// Persistent recurrent kernel: 32 blocks, block bid owns hidden cols
// [bid*16,+16) for all 4 gates (64 gate-cols), all 64 batch rows.
// NO fences anywhere: h+flags use relaxed agent atomics (cache-bypass bits,
// no buffer_inv/buffer_wbl2); x/WUt/bias use plain cached loads (immutable,
// L1/L2 stay hot). Ordering: h-stores -> s_waitcnt vmcnt(0) -> barrier ->
// flag store; readers poll flag then issue coherent h loads (branch-dependent,
// so they issue strictly after the flag value returned).
__global__ __launch_bounds__(256, 1) void lstm_persist(
    const float* __restrict__ x, const ushort* __restrict__ WUt,
    const float* __restrict__ bias,
    ushort* __restrict__ h0buf, ushort* __restrict__ h1buf,
    float* __restrict__ cg, int* __restrict__ flags,
    float* __restrict__ out)
{
    __shared__ float glt[64][68];   // [gatecol][batch] transposed gate staging
    __shared__ float clds[64][16];  // cell state, block-resident all 1024 steps

    int bid = blockIdx.x;
    int tid = threadIdx.x;
    int wid = tid >> 6, lane = tid & 63;
    int wr = wid >> 1, wc = wid & 1;          // wave = [32 batch, 32 gatecol]
    int m = lane & 15, q = lane >> 4;

    // gate-col c = wc*32 + ct*16 + m  ->  WUt row = (wc*2+ct)*H_ + bid*16 + m
    const ushort* wrow[2];
    s16x8 bU[2][16];                           // persistent U-slice: 128 VGPRs
    #pragma unroll
    for (int ct = 0; ct < 2; ++ct) {
        const ushort* bp = WUt + (size_t)((wc * 2 + ct) * H_ + bid * 16 + m) * KTOT + q * 8;
        wrow[ct] = bp;                         // W part (k in [0,512))
        #pragma unroll
        for (int kk = 0; kk < 16; ++kk)
            bU[ct][kk] = *(const s16x8*)(bp + 512 + kk * 32);
    }

    // pointwise role: thread -> (batch pb, 4 hidden cols at pj)
    int pb = tid >> 2, pj = (tid & 3) << 2;
    *(f32x4*)&clds[pb][pj] = *(const f32x4*)(cg + (size_t)pb * H_ + bid * 16 + pj);
    f32x4 bgate[4];
    #pragma unroll
    for (int g = 0; g < 4; ++g)
        bgate[g] = *(const f32x4*)(bias + g * H_ + bid * 16 + pj);
    __syncthreads();

    const float* xr0base = x + (size_t)(wr * 32 + m) * S_ * I_ + q * 8;
    const float* xr1base = x + (size_t)(wr * 32 + 16 + m) * S_ * I_ + q * 8;

    int budget = 4 << 20;   // ~4M polls total: wedge -> fast termination, no GPU hang

    for (int ts = 0; ts < S_; ++ts) {
        // 1. x@W for this step (no h dependency; overlaps other blocks' step ts-1)
        const float* xr0 = xr0base + (size_t)ts * I_;
        const float* xr1 = xr1base + (size_t)ts * I_;
        f32x4 acc[2][2] = {};
        #pragma unroll
        for (int kk = 0; kk < 16; ++kk) {
            s16x8 A0 = cvt_frag(xr0 + kk * 32);
            s16x8 A1 = cvt_frag(xr1 + kk * 32);
            s16x8 B0 = *(const s16x8*)(wrow[0] + kk * 32);
            s16x8 B1 = *(const s16x8*)(wrow[1] + kk * 32);
            acc[0][0] = __builtin_amdgcn_mfma_f32_16x16x32_bf16(A0, B0, acc[0][0], 0, 0, 0);
            acc[0][1] = __builtin_amdgcn_mfma_f32_16x16x32_bf16(A0, B1, acc[0][1], 0, 0, 0);
            acc[1][0] = __builtin_amdgcn_mfma_f32_16x16x32_bf16(A1, B0, acc[1][0], 0, 0, 0);
            acc[1][1] = __builtin_amdgcn_mfma_f32_16x16x32_bf16(A1, B1, acc[1][1], 0, 0, 0);
        }

        // 2. wait until every block published h_ts (flag >= ts). RELAXED poll:
        //    no buffer_inv per iteration (the acquire-poll was the 30us/step bug).
        if (tid < NBLK) {
            while (budget > 0 &&
                   __hip_atomic_load(&flags[tid], __ATOMIC_RELAXED,
                                     __HIP_MEMORY_SCOPE_AGENT) < ts) {
                __builtin_amdgcn_s_sleep(1);
                --budget;
            }
        }
        __syncthreads();

        // 3. h @ U-slice (A via coherent loads, B from VGPRs) accumulated on top
        const ushort* hrow = (ts & 1) ? h1buf : h0buf;
        const ushort* ha0 = hrow + (size_t)(wr * 32 + m) * H_ + q * 8;
        const ushort* ha1 = hrow + (size_t)(wr * 32 + 16 + m) * H_ + q * 8;
        #pragma unroll
        for (int kk = 0; kk < 16; ++kk) {
            s16x8 A0 = ld_h16(ha0 + kk * 32);
            s16x8 A1 = ld_h16(ha1 + kk * 32);
            acc[0][0] = __builtin_amdgcn_mfma_f32_16x16x32_bf16(A0, bU[0][kk], acc[0][0], 0, 0, 0);
            acc[0][1] = __builtin_amdgcn_mfma_f32_16x16x32_bf16(A0, bU[1][kk], acc[0][1], 0, 0, 0);
            acc[1][0] = __builtin_amdgcn_mfma_f32_16x16x32_bf16(A1, bU[0][kk], acc[1][0], 0, 0, 0);
            acc[1][1] = __builtin_amdgcn_mfma_f32_16x16x32_bf16(A1, bU[1][kk], acc[1][1], 0, 0, 0);
        }

        // 4. stage gates transposed: glt[gatecol][batch]
        #pragma unroll
        for (int bt = 0; bt < 2; ++bt)
            #pragma unroll
            for (int ct = 0; ct < 2; ++ct)
                *(f32x4*)&glt[wc * 32 + ct * 16 + m][wr * 32 + bt * 16 + q * 4] = acc[bt][ct];
        __syncthreads();

        // 5. pointwise: gates -> c,h  (c stays in LDS)
        float hv4[4], cv4[4];
        #pragma unroll
        for (int jj = 0; jj < 4; ++jj) {
            int jl = pj + jj;
            float gi = glt[jl][pb]      + bgate[0][jj];
            float gf = glt[16 + jl][pb] + bgate[1][jj];
            float gg = glt[32 + jl][pb] + bgate[2][jj];
            float go = glt[48 + jl][pb] + bgate[3][jj];
            float iv = 1.f / (1.f + __expf(-gi));
            float fv = 1.f / (1.f + __expf(-gf));
            float gv = tanhf(gg);
            float ov = 1.f / (1.f + __expf(-go));
            float cv = fv * clds[pb][jl] + iv * gv;
            clds[pb][jl] = cv;
            float hv = ov * tanhf(cv);
            hv4[jj] = hv; cv4[jj] = cv;
        }

        // publish h_{ts+1} slice: one 8B write-through relaxed atomic store
        union { ushort4 s; unsigned long long u; } hs;
        hs.s.x = f2bf(hv4[0]); hs.s.y = f2bf(hv4[1]);
        hs.s.z = f2bf(hv4[2]); hs.s.w = f2bf(hv4[3]);
        ushort* hnext = ((ts + 1) & 1) ? h1buf : h0buf;
        __hip_atomic_store((unsigned long long*)(hnext + (size_t)pb * H_ + bid * 16 + pj),
                           hs.u, __ATOMIC_RELAXED, __HIP_MEMORY_SCOPE_AGENT);

        // 6. order: own store complete -> all threads' stores complete -> signal
        asm volatile("s_waitcnt vmcnt(0)" ::: "memory");
        __syncthreads();
        if (tid == 0)
            __hip_atomic_store(&flags[bid], ts + 1, __ATOMIC_RELAXED,
                               __HIP_MEMORY_SCOPE_AGENT);

        // 7. deferred (off critical path): hidden_seq / final h_t,c_t stores
        f32x4 hvv = {hv4[0], hv4[1], hv4[2], hv4[3]};
        *(f32x4*)(out + ((size_t)pb * S_ + ts) * H_ + bid * 16 + pj) = hvv;
        if (ts == S_ - 1) {
            f32x4 cvv = {cv4[0], cv4[1], cv4[2], cv4[3]};
            size_t tail = (size_t)B_ * S_ * H_;
            *(f32x4*)(out + tail + (size_t)pb * H_ + bid * 16 + pj) = hvv;
            *(f32x4*)(out + tail + (size_t)B_ * H_ + (size_t)pb * H_ + bid * 16 + pj) = cvv;
        }
    }

    // persist cell state (graph-replay safe: init_all re-zeros each run)
    __syncthreads();
    *(f32x4*)(cg + (size_t)pb * H_ + bid * 16 + pj) = *(const f32x4*)&clds[pb][pj];
}

extern "C" void kernel_launch(void* const* d_in, const int* in_sizes, int n_in,
                              void* d_out, int out_size, void* d_ws, size_t ws_size,
                              hipStream_t stream) {
    const float* x    = (const float*)d_in[0];
    const float* W    = (const float*)d_in[1];
    const float* U    = (const float*)d_in[2];
    const float* bias = (const float*)d_in[3];
    float* out = (float*)d_out;
    char* ws = (char*)d_ws;

    // ws layout (~4.46 MiB): WUt 4MiB | h0 64K | h1 64K | c 128K | flags 4K
    ushort* WUt = (ushort*)ws;
    size_t off = (size_t)4 * 1024 * 1024;
    ushort* h0 = (ushort*)(ws + off); off += (size_t)B_ * H_ * sizeof(ushort);
    ushort* h1 = (ushort*)(ws + off); off += (size_t)B_ * H_ * sizeof(ushort);
    float*  cg = (float*)(ws + off);  off += (size_t)B_ * H_ * sizeof(float);
    int* flags = (int*)(ws + off);

    prep_wut<<<dim3(G4 / 32, KTOT / 32), dim3(32, 32), 0, stream>>>(W, U, WUt);
    init_all<<<(B_ * H_) / 256, 256, 0, stream>>>(h0, h1, cg, flags);
    lstm_persist<<<dim3(NBLK), 256, 0, stream>>>(x, WUt, bias, h0, h1, cg,
                                                 flags, out);
}

// Round 4
// 25788.391 us; speedup vs baseline: 1.1887x; 1.0337x over previous
//
#include <hip/hip_runtime.h>
#include <hip/hip_bf16.h>

#define B_   64
#define S_   1024
#define I_   512
#define H_   512
#define G4   2048   // 4*H
#define KTOT 1024   // I_ + H_
#define NBLK 64     // persistent grid (<< 256 CUs -> co-resident)

typedef float f32x4 __attribute__((ext_vector_type(4)));
typedef float f32x2 __attribute__((ext_vector_type(2)));
typedef short s16x8 __attribute__((ext_vector_type(8)));

#define ULD_PITCH 520   // 512 data shorts + 8 pad -> row stride 1040B, bank-quad balanced

__device__ inline ushort f2bf(float f) {
    union { __hip_bfloat16 h; ushort u; } v;
    v.h = __float2bfloat16(f);
    return v.u;
}

__device__ inline s16x8 cvt_frag(const float* p) {
    float4 a = *(const float4*)p;
    float4 b = *(const float4*)(p + 4);
    s16x8 r;
    r[0] = (short)f2bf(a.x); r[1] = (short)f2bf(a.y);
    r[2] = (short)f2bf(a.z); r[3] = (short)f2bf(a.w);
    r[4] = (short)f2bf(b.x); r[5] = (short)f2bf(b.y);
    r[6] = (short)f2bf(b.z); r[7] = (short)f2bf(b.w);
    return r;
}

// Coherent (agent-scope, cache-bypassing) 16B h-frag load as 2x8B relaxed atomics.
__device__ inline s16x8 ld_h16(const ushort* p) {
    union { unsigned long long u[2]; s16x8 v; } r;
    const unsigned long long* q = (const unsigned long long*)p;
    r.u[0] = __hip_atomic_load(q,     __ATOMIC_RELAXED, __HIP_MEMORY_SCOPE_AGENT);
    r.u[1] = __hip_atomic_load(q + 1, __ATOMIC_RELAXED, __HIP_MEMORY_SCOPE_AGENT);
    return r.v;
}

// WUt[g][k] = (k<512 ? W[k][g] : U[k-512][g]) as bf16.  [2048][1024]
__global__ __launch_bounds__(1024) void prep_wut(const float* __restrict__ W,
                                                 const float* __restrict__ U,
                                                 ushort* __restrict__ WUt) {
    __shared__ ushort lds[32][33];
    int g0 = blockIdx.x * 32, k0 = blockIdx.y * 32;
    int tx = threadIdx.x, ty = threadIdx.y;
    int k = k0 + ty, g = g0 + tx;
    float v = (k < I_) ? W[(size_t)k * G4 + g] : U[(size_t)(k - I_) * G4 + g];
    lds[ty][tx] = f2bf(v);
    __syncthreads();
    WUt[(size_t)(g0 + ty) * KTOT + k0 + tx] = lds[tx][ty];
}

__global__ __launch_bounds__(256) void init_all(ushort* __restrict__ h0,
                                                ushort* __restrict__ h1,
                                                float* __restrict__ cg,
                                                int* __restrict__ flags) {
    int i = blockIdx.x * 256 + threadIdx.x;   // 32768 total
    h0[i] = 0;
    h1[i] = 0;
    cg[i] = 0.0f;
    if (i < NBLK) flags[i] = 0;
}

// Persistent recurrent kernel: 64 blocks; block bid owns hidden cols
// [bid*8,+8) for all 4 gates (32 local gate-cols lg: gate=lg>>3, col=lg&7),
// all 64 batch rows. U-slice lives in LDS (32KB, bank-quad-balanced pad);
// W-slice streamed from L1/L2 (hot). VGPRs stay free -> deep x-load pipelining.
// Sync: relaxed agent atomics for h+flags (no buffer_inv/wbl2); h-stores ->
// s_waitcnt vmcnt(0) -> barrier -> flag store; readers poll then load coherent.
__global__ __launch_bounds__(256, 1) void lstm_persist(
    const float* __restrict__ x, const ushort* __restrict__ WUt,
    const float* __restrict__ bias,
    ushort* __restrict__ h0buf, ushort* __restrict__ h1buf,
    float* __restrict__ cg, int* __restrict__ flags,
    float* __restrict__ out)
{
    __shared__ ushort ulds[32 * ULD_PITCH];   // U slice [32 gcol][512 +8 pad]  (~32.5 KB)
    __shared__ float glt[32][68];             // [gcol][batch] gate staging (8.5 KB)
    __shared__ float clds[64][9];             // cell state (2.25 KB)

    int bid = blockIdx.x;
    int tid = threadIdx.x;
    int wid = tid >> 6, lane = tid & 63;
    int wr = wid >> 1, wc = wid & 1;          // wave: rows [wr*32,+32) x gcols [wc*16,+16)
    int m = lane & 15, q = lane >> 4;
    int lg = wc * 16 + m;                     // lane's local gate-col

    // per-lane W row pointer (W part of WUt, k in [0,512))
    const ushort* wp = WUt + (size_t)((lg >> 3) * H_ + bid * 8 + (lg & 7)) * KTOT + q * 8;

    // ---- stage U slice into LDS once (row r = local gcol) ----
    {
        int r = tid >> 3, seg = tid & 7;
        const ushort* src = WUt + (size_t)((r >> 3) * H_ + bid * 8 + (r & 7)) * KTOT + 512 + seg * 64;
        ushort* dst = ulds + r * ULD_PITCH + seg * 64;
        #pragma unroll
        for (int i = 0; i < 8; ++i)
            *(s16x8*)(dst + i * 8) = *(const s16x8*)(src + i * 8);
    }
    const ushort* up = ulds + lg * ULD_PITCH + q * 8;   // lane's U-frag base

    // pointwise role: thread -> (batch pb, cols pc, pc+1)
    int pb = tid >> 2, pc = (tid & 3) * 2;
    clds[pb][pc]     = cg[(size_t)pb * H_ + bid * 8 + pc];
    clds[pb][pc + 1] = cg[(size_t)pb * H_ + bid * 8 + pc + 1];
    float bg_[4][2];
    #pragma unroll
    for (int g = 0; g < 4; ++g) {
        bg_[g][0] = bias[g * H_ + bid * 8 + pc];
        bg_[g][1] = bias[g * H_ + bid * 8 + pc + 1];
    }
    __syncthreads();

    const float* xr0base = x + (size_t)(wr * 32 + m) * S_ * I_ + q * 8;
    const float* xr1base = x + (size_t)(wr * 32 + 16 + m) * S_ * I_ + q * 8;

    int budget = 1 << 21;   // bounded spin: wedge -> fast termination, no GPU hang

    for (int ts = 0; ts < S_; ++ts) {
        // 1. x@W for this step (no h dependency; overlaps other blocks' publish)
        const float* xa = xr0base + (size_t)ts * I_;
        const float* xb = xr1base + (size_t)ts * I_;
        f32x4 acc0 = {0.f, 0.f, 0.f, 0.f};
        f32x4 acc1 = {0.f, 0.f, 0.f, 0.f};
        #pragma unroll
        for (int kk = 0; kk < 16; ++kk) {
            s16x8 A0 = cvt_frag(xa + kk * 32);
            s16x8 A1 = cvt_frag(xb + kk * 32);
            s16x8 Bw = *(const s16x8*)(wp + kk * 32);
            acc0 = __builtin_amdgcn_mfma_f32_16x16x32_bf16(A0, Bw, acc0, 0, 0, 0);
            acc1 = __builtin_amdgcn_mfma_f32_16x16x32_bf16(A1, Bw, acc1, 0, 0, 0);
        }

        // 2. wait until every block published h_ts (flag >= ts). Relaxed poll.
        if (tid < NBLK) {
            while (budget > 0 &&
                   __hip_atomic_load(&flags[tid], __ATOMIC_RELAXED,
                                     __HIP_MEMORY_SCOPE_AGENT) < ts) {
                __builtin_amdgcn_s_sleep(1);
                --budget;
            }
        }
        __syncthreads();

        // 3. h @ U-slice: A coherent loads, B from LDS (bank-balanced ds_read_b128)
        const ushort* hrow = (ts & 1) ? h1buf : h0buf;
        const ushort* ha0 = hrow + (size_t)(wr * 32 + m) * H_ + q * 8;
        const ushort* ha1 = ha0 + (size_t)16 * H_;
        #pragma unroll
        for (int kk = 0; kk < 16; ++kk) {
            s16x8 A0 = ld_h16(ha0 + kk * 32);
            s16x8 A1 = ld_h16(ha1 + kk * 32);
            s16x8 Bu = *(const s16x8*)(up + kk * 32);
            acc0 = __builtin_amdgcn_mfma_f32_16x16x32_bf16(A0, Bu, acc0, 0, 0, 0);
            acc1 = __builtin_amdgcn_mfma_f32_16x16x32_bf16(A1, Bu, acc1, 0, 0, 0);
        }

        // 4. stage gates transposed: glt[gcol][batch]
        *(f32x4*)&glt[lg][wr * 32 + q * 4]      = acc0;
        *(f32x4*)&glt[lg][wr * 32 + 16 + q * 4] = acc1;
        __syncthreads();

        // 5. pointwise: gates -> c,h  (c stays in LDS)
        float hv[2], cv[2];
        #pragma unroll
        for (int jj = 0; jj < 2; ++jj) {
            int c = pc + jj;
            float gi = glt[c][pb]      + bg_[0][jj];
            float gf = glt[8 + c][pb]  + bg_[1][jj];
            float gg = glt[16 + c][pb] + bg_[2][jj];
            float go = glt[24 + c][pb] + bg_[3][jj];
            float iv = 1.f / (1.f + __expf(-gi));
            float fv = 1.f / (1.f + __expf(-gf));
            float gv = tanhf(gg);
            float ov = 1.f / (1.f + __expf(-go));
            float cc = fv * clds[pb][c] + iv * gv;
            clds[pb][c] = cc;
            cv[jj] = cc;
            hv[jj] = ov * tanhf(cc);
        }

        // publish h_{ts+1}: one 4B write-through relaxed atomic store (2 bf16)
        union { ushort u2[2]; uint u; } hsv;
        hsv.u2[0] = f2bf(hv[0]);
        hsv.u2[1] = f2bf(hv[1]);
        ushort* hnext = ((ts + 1) & 1) ? h1buf : h0buf;
        __hip_atomic_store((uint*)(hnext + (size_t)pb * H_ + bid * 8 + pc),
                           hsv.u, __ATOMIC_RELAXED, __HIP_MEMORY_SCOPE_AGENT);

        // 6. order: own store complete -> all threads' stores complete -> signal
        asm volatile("s_waitcnt vmcnt(0)" ::: "memory");
        __syncthreads();
        if (tid == 0)
            __hip_atomic_store(&flags[bid], ts + 1, __ATOMIC_RELAXED,
                               __HIP_MEMORY_SCOPE_AGENT);

        // 7. deferred (off critical path): hidden_seq / final h_t,c_t stores
        f32x2 hq = {hv[0], hv[1]};
        *(f32x2*)(out + ((size_t)pb * S_ + ts) * H_ + bid * 8 + pc) = hq;
        if (ts == S_ - 1) {
            f32x2 cq = {cv[0], cv[1]};
            size_t tail = (size_t)B_ * S_ * H_;
            *(f32x2*)(out + tail + (size_t)pb * H_ + bid * 8 + pc) = hq;
            *(f32x2*)(out + tail + (size_t)B_ * H_ + (size_t)pb * H_ + bid * 8 + pc) = cq;
        }
    }

    // persist cell state (graph-replay safe: init_all re-zeros each run)
    __syncthreads();
    cg[(size_t)pb * H_ + bid * 8 + pc]     = clds[pb][pc];
    cg[(size_t)pb * H_ + bid * 8 + pc + 1] = clds[pb][pc + 1];
}

extern "C" void kernel_launch(void* const* d_in, const int* in_sizes, int n_in,
                              void* d_out, int out_size, void* d_ws, size_t ws_size,
                              hipStream_t stream) {
    const float* x    = (const float*)d_in[0];
    const float* W    = (const float*)d_in[1];
    const float* U    = (const float*)d_in[2];
    const float* bias = (const float*)d_in[3];
    float* out = (float*)d_out;
    char* ws = (char*)d_ws;

    // ws layout (~4.46 MiB): WUt 4MiB | h0 64K | h1 64K | c 128K | flags 4K
    ushort* WUt = (ushort*)ws;
    size_t off = (size_t)4 * 1024 * 1024;
    ushort* h0 = (ushort*)(ws + off); off += (size_t)B_ * H_ * sizeof(ushort);
    ushort* h1 = (ushort*)(ws + off); off += (size_t)B_ * H_ * sizeof(ushort);
    float*  cg = (float*)(ws + off);  off += (size_t)B_ * H_ * sizeof(float);
    int* flags = (int*)(ws + off);

    prep_wut<<<dim3(G4 / 32, KTOT / 32), dim3(32, 32), 0, stream>>>(W, U, WUt);
    init_all<<<(B_ * H_) / 256, 256, 0, stream>>>(h0, h1, cg, flags);
    lstm_persist<<<dim3(NBLK), 256, 0, stream>>>(x, WUt, bias, h0, h1, cg,
                                                 flags, out);
}

// Round 5
// 13452.261 us; speedup vs baseline: 2.2789x; 1.9170x over previous
//
#include <hip/hip_runtime.h>
#include <hip/hip_bf16.h>

#define B_   64
#define S_   1024
#define I_   512
#define H_   512
#define G4   2048   // 4*H
#define KTOT 1024   // I_ + H_
#define NBLK 64     // persistent grid (<< 256 CUs -> co-resident)

typedef float f32x4 __attribute__((ext_vector_type(4)));
typedef float f32x2 __attribute__((ext_vector_type(2)));
typedef short s16x8 __attribute__((ext_vector_type(8)));

#define ULD_PITCH 520   // 512 data shorts + 8 pad

__device__ inline ushort f2bf(float f) {
    union { __hip_bfloat16 h; ushort u; } v;
    v.h = __float2bfloat16(f);
    return v.u;
}

__device__ inline s16x8 cvt_frag(const float* p) {
    float4 a = *(const float4*)p;
    float4 b = *(const float4*)(p + 4);
    s16x8 r;
    r[0] = (short)f2bf(a.x); r[1] = (short)f2bf(a.y);
    r[2] = (short)f2bf(a.z); r[3] = (short)f2bf(a.w);
    r[4] = (short)f2bf(b.x); r[5] = (short)f2bf(b.y);
    r[6] = (short)f2bf(b.z); r[7] = (short)f2bf(b.w);
    return r;
}

// Coherent (agent-scope, cache-bypassing) 16B h-frag load as 2x8B relaxed atomics.
__device__ inline s16x8 ld_h16(const ushort* p) {
    union { unsigned long long u[2]; s16x8 v; } r;
    const unsigned long long* q = (const unsigned long long*)p;
    r.u[0] = __hip_atomic_load(q,     __ATOMIC_RELAXED, __HIP_MEMORY_SCOPE_AGENT);
    r.u[1] = __hip_atomic_load(q + 1, __ATOMIC_RELAXED, __HIP_MEMORY_SCOPE_AGENT);
    return r.v;
}

// WUt[g][k] = (k<512 ? W[k][g] : U[k-512][g]) as bf16.  [2048][1024]
__global__ __launch_bounds__(1024) void prep_wut(const float* __restrict__ W,
                                                 const float* __restrict__ U,
                                                 ushort* __restrict__ WUt) {
    __shared__ ushort lds[32][33];
    int g0 = blockIdx.x * 32, k0 = blockIdx.y * 32;
    int tx = threadIdx.x, ty = threadIdx.y;
    int k = k0 + ty, g = g0 + tx;
    float v = (k < I_) ? W[(size_t)k * G4 + g] : U[(size_t)(k - I_) * G4 + g];
    lds[ty][tx] = f2bf(v);
    __syncthreads();
    WUt[(size_t)(g0 + ty) * KTOT + k0 + tx] = lds[tx][ty];
}

// xbf = bf16(x), same [B][S][I] layout. One-time full-BW convert.
__global__ __launch_bounds__(256) void prep_xbf(const float* __restrict__ x,
                                                ushort* __restrict__ xbf) {
    size_t stride = (size_t)gridDim.x * 256 * 8;
    size_t total = (size_t)B_ * S_ * I_;
    for (size_t i = ((size_t)blockIdx.x * 256 + threadIdx.x) * 8; i < total; i += stride)
        *(s16x8*)(xbf + i) = cvt_frag(x + i);
}

__global__ __launch_bounds__(256) void init_all(ushort* __restrict__ h0,
                                                ushort* __restrict__ h1,
                                                float* __restrict__ cg,
                                                int* __restrict__ flags) {
    int i = blockIdx.x * 256 + threadIdx.x;   // 32768 total
    h0[i] = 0;
    h1[i] = 0;
    cg[i] = 0.0f;
    if (i < NBLK) flags[i] = 0;
}

// Persistent recurrent kernel: 64 blocks; block bid owns hidden cols
// [bid*8,+8) for all 4 gates (32 local gate-cols), all 64 batch rows.
// XBF=true: A-frags loaded bf16 direct from xbf, ALL 32 loads hoisted into
// registers before the MFMA loop (one HBM latency round instead of ~40).
// Sync: relaxed agent atomics (no buffer_inv/wbl2); h-stores -> vmcnt(0) ->
// barrier -> flag store; readers poll flag then issue coherent h loads.
template <bool XBF>
__global__ __launch_bounds__(256, 1) void lstm_persist(
    const float* __restrict__ x, const ushort* __restrict__ xbf,
    const ushort* __restrict__ WUt, const float* __restrict__ bias,
    ushort* __restrict__ h0buf, ushort* __restrict__ h1buf,
    float* __restrict__ cg, int* __restrict__ flags,
    float* __restrict__ out)
{
    __shared__ ushort ulds[32 * ULD_PITCH];   // U slice [32 gcol][512+8]  (~32.5 KB)
    __shared__ float glt[32][68];             // [gcol][batch] gate staging
    __shared__ float clds[64][9];             // cell state, block-resident

    int bid = blockIdx.x;
    int tid = threadIdx.x;
    int wid = tid >> 6, lane = tid & 63;
    int wr = wid >> 1, wc = wid & 1;          // wave: rows [wr*32,+32) x gcols [wc*16,+16)
    int m = lane & 15, q = lane >> 4;
    int lg = wc * 16 + m;                     // lane's local gate-col
    int r0 = wr * 32 + m, r1 = r0 + 16;       // lane's two batch rows

    // per-lane W row pointer (W part of WUt, k in [0,512))
    const ushort* wp = WUt + (size_t)((lg >> 3) * H_ + bid * 8 + (lg & 7)) * KTOT + q * 8;

    // stage U slice into LDS once
    {
        int r = tid >> 3, seg = tid & 7;
        const ushort* src = WUt + (size_t)((r >> 3) * H_ + bid * 8 + (r & 7)) * KTOT + 512 + seg * 64;
        ushort* dst = ulds + r * ULD_PITCH + seg * 64;
        #pragma unroll
        for (int i = 0; i < 8; ++i)
            *(s16x8*)(dst + i * 8) = *(const s16x8*)(src + i * 8);
    }
    const ushort* up = ulds + lg * ULD_PITCH + q * 8;

    // pointwise role: thread -> (batch pb, cols pc, pc+1)
    int pb = tid >> 2, pc = (tid & 3) * 2;
    clds[pb][pc]     = cg[(size_t)pb * H_ + bid * 8 + pc];
    clds[pb][pc + 1] = cg[(size_t)pb * H_ + bid * 8 + pc + 1];
    float bg_[4][2];
    #pragma unroll
    for (int g = 0; g < 4; ++g) {
        bg_[g][0] = bias[g * H_ + bid * 8 + pc];
        bg_[g][1] = bias[g * H_ + bid * 8 + pc + 1];
    }
    __syncthreads();

    int budget = 1 << 21;   // bounded spin: wedge -> fast termination, no GPU hang

    for (int ts = 0; ts < S_; ++ts) {
        // 1. x@W for this step, h-independent (overlaps other blocks' publish).
        f32x4 acc0 = {0.f, 0.f, 0.f, 0.f};
        f32x4 acc1 = {0.f, 0.f, 0.f, 0.f};
        if constexpr (XBF) {
            // burst-load all 32 A-frags -> 32 loads in flight (one latency round)
            s16x8 afr[2][16];
            const ushort* xa = xbf + ((size_t)r0 * S_ + ts) * I_ + q * 8;
            const ushort* xb = xbf + ((size_t)r1 * S_ + ts) * I_ + q * 8;
            #pragma unroll
            for (int kk = 0; kk < 16; ++kk) {
                afr[0][kk] = *(const s16x8*)(xa + kk * 32);
                afr[1][kk] = *(const s16x8*)(xb + kk * 32);
            }
            #pragma unroll
            for (int kk = 0; kk < 16; ++kk) {
                s16x8 Bw = *(const s16x8*)(wp + kk * 32);
                acc0 = __builtin_amdgcn_mfma_f32_16x16x32_bf16(afr[0][kk], Bw, acc0, 0, 0, 0);
                acc1 = __builtin_amdgcn_mfma_f32_16x16x32_bf16(afr[1][kk], Bw, acc1, 0, 0, 0);
            }
        } else {
            const float* xa = x + ((size_t)r0 * S_ + ts) * I_ + q * 8;
            const float* xb = x + ((size_t)r1 * S_ + ts) * I_ + q * 8;
            #pragma unroll
            for (int kk = 0; kk < 16; ++kk) {
                s16x8 A0 = cvt_frag(xa + kk * 32);
                s16x8 A1 = cvt_frag(xb + kk * 32);
                s16x8 Bw = *(const s16x8*)(wp + kk * 32);
                acc0 = __builtin_amdgcn_mfma_f32_16x16x32_bf16(A0, Bw, acc0, 0, 0, 0);
                acc1 = __builtin_amdgcn_mfma_f32_16x16x32_bf16(A1, Bw, acc1, 0, 0, 0);
            }
        }

        // 2. wait until every block published h_ts (flag >= ts). Relaxed poll.
        if (tid < NBLK) {
            while (budget > 0 &&
                   __hip_atomic_load(&flags[tid], __ATOMIC_RELAXED,
                                     __HIP_MEMORY_SCOPE_AGENT) < ts) {
                __builtin_amdgcn_s_sleep(1);
                --budget;
            }
        }
        __syncthreads();

        // 3. h @ U-slice: burst all 32 coherent h loads, then MFMA from LDS-U.
        {
            const ushort* hrow = (ts & 1) ? h1buf : h0buf;
            const ushort* ha0 = hrow + (size_t)r0 * H_ + q * 8;
            const ushort* ha1 = hrow + (size_t)r1 * H_ + q * 8;
            s16x8 hfr[2][16];
            #pragma unroll
            for (int kk = 0; kk < 16; ++kk) {
                hfr[0][kk] = ld_h16(ha0 + kk * 32);
                hfr[1][kk] = ld_h16(ha1 + kk * 32);
            }
            #pragma unroll
            for (int kk = 0; kk < 16; ++kk) {
                s16x8 Bu = *(const s16x8*)(up + kk * 32);
                acc0 = __builtin_amdgcn_mfma_f32_16x16x32_bf16(hfr[0][kk], Bu, acc0, 0, 0, 0);
                acc1 = __builtin_amdgcn_mfma_f32_16x16x32_bf16(hfr[1][kk], Bu, acc1, 0, 0, 0);
            }
        }

        // 4. stage gates transposed: glt[gcol][batch]
        *(f32x4*)&glt[lg][wr * 32 + q * 4]      = acc0;
        *(f32x4*)&glt[lg][wr * 32 + 16 + q * 4] = acc1;
        __syncthreads();

        // 5. pointwise: gates -> c,h  (c stays in LDS)
        float hv[2], cv[2];
        #pragma unroll
        for (int jj = 0; jj < 2; ++jj) {
            int c = pc + jj;
            float gi = glt[c][pb]      + bg_[0][jj];
            float gf = glt[8 + c][pb]  + bg_[1][jj];
            float gg = glt[16 + c][pb] + bg_[2][jj];
            float go = glt[24 + c][pb] + bg_[3][jj];
            float iv = 1.f / (1.f + __expf(-gi));
            float fv = 1.f / (1.f + __expf(-gf));
            float gv = tanhf(gg);
            float ov = 1.f / (1.f + __expf(-go));
            float cc = fv * clds[pb][c] + iv * gv;
            clds[pb][c] = cc;
            cv[jj] = cc;
            hv[jj] = ov * tanhf(cc);
        }

        // publish h_{ts+1}: one 4B write-through relaxed atomic store (2 bf16)
        union { ushort u2[2]; uint u; } hsv;
        hsv.u2[0] = f2bf(hv[0]);
        hsv.u2[1] = f2bf(hv[1]);
        ushort* hnext = ((ts + 1) & 1) ? h1buf : h0buf;
        __hip_atomic_store((uint*)(hnext + (size_t)pb * H_ + bid * 8 + pc),
                           hsv.u, __ATOMIC_RELAXED, __HIP_MEMORY_SCOPE_AGENT);

        // 6. order: own store complete -> all threads' stores complete -> signal
        asm volatile("s_waitcnt vmcnt(0)" ::: "memory");
        __syncthreads();
        if (tid == 0)
            __hip_atomic_store(&flags[bid], ts + 1, __ATOMIC_RELAXED,
                               __HIP_MEMORY_SCOPE_AGENT);

        // 7. deferred (off critical path): hidden_seq / final h_t,c_t stores
        f32x2 hq = {hv[0], hv[1]};
        *(f32x2*)(out + ((size_t)pb * S_ + ts) * H_ + bid * 8 + pc) = hq;
        if (ts == S_ - 1) {
            f32x2 cq = {cv[0], cv[1]};
            size_t tail = (size_t)B_ * S_ * H_;
            *(f32x2*)(out + tail + (size_t)pb * H_ + bid * 8 + pc) = hq;
            *(f32x2*)(out + tail + (size_t)B_ * H_ + (size_t)pb * H_ + bid * 8 + pc) = cq;
        }
    }

    // persist cell state (graph-replay safe: init_all re-zeros each run)
    __syncthreads();
    cg[(size_t)pb * H_ + bid * 8 + pc]     = clds[pb][pc];
    cg[(size_t)pb * H_ + bid * 8 + pc + 1] = clds[pb][pc + 1];
}

extern "C" void kernel_launch(void* const* d_in, const int* in_sizes, int n_in,
                              void* d_out, int out_size, void* d_ws, size_t ws_size,
                              hipStream_t stream) {
    const float* x    = (const float*)d_in[0];
    const float* W    = (const float*)d_in[1];
    const float* U    = (const float*)d_in[2];
    const float* bias = (const float*)d_in[3];
    float* out = (float*)d_out;
    char* ws = (char*)d_ws;

    // ws layout: WUt 4MiB | h0 64K | h1 64K | c 128K | flags 4K | xbf 64MiB
    ushort* WUt = (ushort*)ws;
    size_t off = (size_t)4 * 1024 * 1024;
    ushort* h0 = (ushort*)(ws + off); off += (size_t)B_ * H_ * sizeof(ushort);
    ushort* h1 = (ushort*)(ws + off); off += (size_t)B_ * H_ * sizeof(ushort);
    float*  cg = (float*)(ws + off);  off += (size_t)B_ * H_ * sizeof(float);
    int* flags = (int*)(ws + off);    off += 4096;
    ushort* xbf = (ushort*)(ws + off);
    size_t need = off + (size_t)B_ * S_ * I_ * sizeof(ushort);   // ~68.3 MiB
    bool use_xbf = (ws_size >= need);

    prep_wut<<<dim3(G4 / 32, KTOT / 32), dim3(32, 32), 0, stream>>>(W, U, WUt);
    init_all<<<(B_ * H_) / 256, 256, 0, stream>>>(h0, h1, cg, flags);

    if (use_xbf) {
        prep_xbf<<<4096, 256, 0, stream>>>(x, xbf);
        lstm_persist<true><<<dim3(NBLK), 256, 0, stream>>>(
            x, xbf, WUt, bias, h0, h1, cg, flags, out);
    } else {
        lstm_persist<false><<<dim3(NBLK), 256, 0, stream>>>(
            x, xbf, WUt, bias, h0, h1, cg, flags, out);
    }
}

// Round 8
// 12276.122 us; speedup vs baseline: 2.4972x; 1.0958x over previous
//
#include <hip/hip_runtime.h>
#include <hip/hip_bf16.h>

#define B_   64
#define S_   1024
#define I_   512
#define H_   512
#define G4   2048   // 4*H
#define KTOT 1024   // I_ + H_
#define NBLK 64     // persistent grid (<< 256 CUs -> co-resident)

typedef float f32x4 __attribute__((ext_vector_type(4)));
typedef float f32x2 __attribute__((ext_vector_type(2)));
typedef short s16x8 __attribute__((ext_vector_type(8)));

#define ULD_PITCH 520   // 512 data shorts + 8 pad

__device__ inline ushort f2bf(float f) {
    union { __hip_bfloat16 h; ushort u; } v;
    v.h = __float2bfloat16(f);
    return v.u;
}

__device__ inline s16x8 cvt_frag(const float* p) {
    float4 a = *(const float4*)p;
    float4 b = *(const float4*)(p + 4);
    s16x8 r;
    r[0] = (short)f2bf(a.x); r[1] = (short)f2bf(a.y);
    r[2] = (short)f2bf(a.z); r[3] = (short)f2bf(a.w);
    r[4] = (short)f2bf(b.x); r[5] = (short)f2bf(b.y);
    r[6] = (short)f2bf(b.z); r[7] = (short)f2bf(b.w);
    return r;
}

// Coherent (agent-scope, cache-bypassing) 16B h-frag load as 2x8B relaxed atomics.
__device__ inline s16x8 ld_h16(const ushort* p) {
    union { unsigned long long u[2]; s16x8 v; } r;
    const unsigned long long* q = (const unsigned long long*)p;
    r.u[0] = __hip_atomic_load(q,     __ATOMIC_RELAXED, __HIP_MEMORY_SCOPE_AGENT);
    r.u[1] = __hip_atomic_load(q + 1, __ATOMIC_RELAXED, __HIP_MEMORY_SCOPE_AGENT);
    return r.v;
}

// Async global->LDS DMA, 16B per lane. LDS dest = wave-uniform base + lane*16
// (HW rule); global src is per-lane. Tracked by the issuing wave's vmcnt.
__device__ inline void dma16(const ushort* g, ushort* l) {
    __builtin_amdgcn_global_load_lds(
        (const __attribute__((address_space(1))) void*)g,
        (__attribute__((address_space(3))) void*)l,
        16, 0, 0);
}

// WUt[g][k] = (k<512 ? W[k][g] : U[k-512][g]) as bf16.  [2048][1024]
__global__ __launch_bounds__(1024) void prep_wut(const float* __restrict__ W,
                                                 const float* __restrict__ U,
                                                 ushort* __restrict__ WUt) {
    __shared__ ushort lds[32][33];
    int g0 = blockIdx.x * 32, k0 = blockIdx.y * 32;
    int tx = threadIdx.x, ty = threadIdx.y;
    int k = k0 + ty, g = g0 + tx;
    float v = (k < I_) ? W[(size_t)k * G4 + g] : U[(size_t)(k - I_) * G4 + g];
    lds[ty][tx] = f2bf(v);
    __syncthreads();
    WUt[(size_t)(g0 + ty) * KTOT + k0 + tx] = lds[tx][ty];
}

// xbf = bf16(x), same [B][S][I] layout. One-time full-BW convert.
__global__ __launch_bounds__(256) void prep_xbf(const float* __restrict__ x,
                                                ushort* __restrict__ xbf) {
    size_t stride = (size_t)gridDim.x * 256 * 8;
    size_t total = (size_t)B_ * S_ * I_;
    for (size_t i = ((size_t)blockIdx.x * 256 + threadIdx.x) * 8; i < total; i += stride)
        *(s16x8*)(xbf + i) = cvt_frag(x + i);
}

__global__ __launch_bounds__(256) void init_all(ushort* __restrict__ h0,
                                                ushort* __restrict__ h1,
                                                float* __restrict__ cg,
                                                int* __restrict__ flags) {
    int i = blockIdx.x * 256 + threadIdx.x;   // 32768 total
    h0[i] = 0;
    h1[i] = 0;
    cg[i] = 0.0f;
    if (i < NBLK) flags[i] = 0;
}

// Persistent recurrent kernel: 64 blocks; block bid owns hidden cols
// [bid*8,+8) for all 4 gates (32 local gate-cols), all 64 batch rows.
// Identical protocol to the 4x-passing R5 kernel. ONE change: per-step x is
// staged into LDS a full step ahead via global_load_lds DMA (zero VGPR cost);
// phase 1 reads A-frags with linear ds_read_b128 instead of chunked HBM bursts.
// DMA ordering needs NO new waits:
//   - poll barrier orders phase-1 LDS reads before the DMA issue (same step)
//   - existing phase-8 vmcnt(0) drain completes the DMA before next step's reads
template <bool XBF>
__global__ __launch_bounds__(256, 1) void lstm_persist(
    const float* __restrict__ x, const ushort* __restrict__ xbf,
    const ushort* __restrict__ WUt, const float* __restrict__ bias,
    ushort* __restrict__ h0buf, ushort* __restrict__ h1buf,
    float* __restrict__ cg, int* __restrict__ flags,
    float* __restrict__ out)
{
    __shared__ ushort xs[64 * 512];           // 64 KB x-stage: inst i -> [i*512, +512)
    __shared__ ushort ulds[32 * ULD_PITCH];   // U slice [32 gcol][512+8]  (~32.5 KB)
    __shared__ float glt[32][68];             // [gcol][batch] gate staging
    __shared__ float clds[64][9];             // cell state, block-resident

    int bid = blockIdx.x;
    int tid = threadIdx.x;
    int wid = tid >> 6, lane = tid & 63;
    int wr = wid >> 1, wc = wid & 1;          // wave: rows [wr*32,+32) x gcols [wc*16,+16)
    int m = lane & 15, q = lane >> 4;
    int lg = wc * 16 + m;                     // lane's local gate-col
    int r0 = wr * 32 + m, r1 = r0 + 16;       // lane's two batch rows

    // per-lane W row pointer (W part of WUt, k in [0,512))
    const ushort* wp = WUt + (size_t)((lg >> 3) * H_ + bid * 8 + (lg & 7)) * KTOT + q * 8;

    // stage U slice into LDS once
    {
        int r = tid >> 3, seg = tid & 7;
        const ushort* src = WUt + (size_t)((r >> 3) * H_ + bid * 8 + (r & 7)) * KTOT + 512 + seg * 64;
        ushort* dst = ulds + r * ULD_PITCH + seg * 64;
        #pragma unroll
        for (int i = 0; i < 8; ++i)
            *(s16x8*)(dst + i * 8) = *(const s16x8*)(src + i * 8);
    }
    const ushort* up = ulds + lg * ULD_PITCH + q * 8;

    // pointwise role: thread -> (batch pb, cols pc, pc+1)
    int pb = tid >> 2, pc = (tid & 3) * 2;
    clds[pb][pc]     = cg[(size_t)pb * H_ + bid * 8 + pc];
    clds[pb][pc + 1] = cg[(size_t)pb * H_ + bid * 8 + pc + 1];
    float bg_[4][2];
    #pragma unroll
    for (int g = 0; g < 4; ++g) {
        bg_[g][0] = bias[g * H_ + bid * 8 + pc];
        bg_[g][1] = bias[g * H_ + bid * 8 + pc + 1];
    }

    // x DMA: inst (g,kk) for this wave-group wr covers rows wr*32+g*16+[0..15],
    // row-bytes [kk*64, +64). Lane l supplies row (l&15), 16B segment (l>>4).
    // LDS inst index i = wr*32 + g*16 + kk (bijective over 64 insts = 64 KB).
    // Only wc==0 waves issue (wc==1 waves read the same LDS afterwards).
    if constexpr (XBF) {
        if (wc == 0) {
            #pragma unroll
            for (int g = 0; g < 2; ++g) {
                const ushort* grow = xbf + (size_t)(wr * 32 + g * 16 + m) * S_ * I_ + q * 8;
                #pragma unroll
                for (int kk = 0; kk < 16; ++kk)
                    dma16(grow + kk * 32, &xs[(wr * 32 + g * 16 + kk) * 512]);
            }
        }
    }
    asm volatile("s_waitcnt vmcnt(0)" ::: "memory");
    __syncthreads();

    // per-lane f32 x bases (fallback path)
    const float* xf0 = x + (size_t)r0 * S_ * I_ + q * 8;
    const float* xf1 = x + (size_t)r1 * S_ * I_ + q * 8;

    int budget = 1 << 21;   // bounded spin: wedge -> fast termination, no GPU hang

    for (int ts = 0; ts < S_; ++ts) {
        // 1. x@W from LDS-staged frags (linear lane*16 addressing, conflict-free)
        f32x4 acc0 = {0.f, 0.f, 0.f, 0.f};
        f32x4 acc1 = {0.f, 0.f, 0.f, 0.f};
        if constexpr (XBF) {
            #pragma unroll
            for (int kk = 0; kk < 16; ++kk) {
                s16x8 A0 = *(const s16x8*)&xs[(wr * 32 + kk) * 512 + lane * 8];
                s16x8 A1 = *(const s16x8*)&xs[(wr * 32 + 16 + kk) * 512 + lane * 8];
                s16x8 Bw = *(const s16x8*)(wp + kk * 32);
                acc0 = __builtin_amdgcn_mfma_f32_16x16x32_bf16(A0, Bw, acc0, 0, 0, 0);
                acc1 = __builtin_amdgcn_mfma_f32_16x16x32_bf16(A1, Bw, acc1, 0, 0, 0);
            }
        } else {
            const float* xa = xf0 + (size_t)ts * I_;
            const float* xb = xf1 + (size_t)ts * I_;
            #pragma unroll
            for (int kk = 0; kk < 16; ++kk) {
                s16x8 A0 = cvt_frag(xa + kk * 32);
                s16x8 A1 = cvt_frag(xb + kk * 32);
                s16x8 Bw = *(const s16x8*)(wp + kk * 32);
                acc0 = __builtin_amdgcn_mfma_f32_16x16x32_bf16(A0, Bw, acc0, 0, 0, 0);
                acc1 = __builtin_amdgcn_mfma_f32_16x16x32_bf16(A1, Bw, acc1, 0, 0, 0);
            }
        }

        // 2. wait until every block published h_ts (flag >= ts). Relaxed poll.
        if (tid < NBLK) {
            while (budget > 0 &&
                   __hip_atomic_load(&flags[tid], __ATOMIC_RELAXED,
                                     __HIP_MEMORY_SCOPE_AGENT) < ts) {
                __builtin_amdgcn_s_sleep(1);
                --budget;
            }
        }
        __syncthreads();   // also orders phase-1 LDS reads before this step's DMA

        // 3. burst-issue all coherent h loads (critical path)
        const ushort* hrow = (ts & 1) ? h1buf : h0buf;
        const ushort* ha0 = hrow + (size_t)r0 * H_ + q * 8;
        const ushort* ha1 = hrow + (size_t)r1 * H_ + q * 8;
        s16x8 hfr[2][16];
        #pragma unroll
        for (int kk = 0; kk < 16; ++kk) {
            hfr[0][kk] = ld_h16(ha0 + kk * 32);
            hfr[1][kk] = ld_h16(ha1 + kk * 32);
        }

        // 4. issue x-DMA for ts+1 (completes under phases 5-8; drained at phase 8)
        if constexpr (XBF) {
            if (wc == 0) {
                int tn = (ts + 1) & (S_ - 1);
                #pragma unroll
                for (int g = 0; g < 2; ++g) {
                    const ushort* grow = xbf
                        + ((size_t)(wr * 32 + g * 16 + m) * S_ + tn) * I_ + q * 8;
                    #pragma unroll
                    for (int kk = 0; kk < 16; ++kk)
                        dma16(grow + kk * 32, &xs[(wr * 32 + g * 16 + kk) * 512]);
                }
            }
        }

        // 5. h @ U-slice (B from LDS)
        #pragma unroll
        for (int kk = 0; kk < 16; ++kk) {
            s16x8 Bu = *(const s16x8*)(up + kk * 32);
            acc0 = __builtin_amdgcn_mfma_f32_16x16x32_bf16(hfr[0][kk], Bu, acc0, 0, 0, 0);
            acc1 = __builtin_amdgcn_mfma_f32_16x16x32_bf16(hfr[1][kk], Bu, acc1, 0, 0, 0);
        }

        // 6. stage gates transposed: glt[gcol][batch]
        *(f32x4*)&glt[lg][wr * 32 + q * 4]      = acc0;
        *(f32x4*)&glt[lg][wr * 32 + 16 + q * 4] = acc1;
        __syncthreads();

        // 7. pointwise: gates -> c,h  (c stays in LDS)
        float hv[2], cv[2];
        #pragma unroll
        for (int jj = 0; jj < 2; ++jj) {
            int c = pc + jj;
            float gi = glt[c][pb]      + bg_[0][jj];
            float gf = glt[8 + c][pb]  + bg_[1][jj];
            float gg = glt[16 + c][pb] + bg_[2][jj];
            float go = glt[24 + c][pb] + bg_[3][jj];
            float iv = 1.f / (1.f + __expf(-gi));
            float fv = 1.f / (1.f + __expf(-gf));
            float gv = tanhf(gg);
            float ov = 1.f / (1.f + __expf(-go));
            float cc = fv * clds[pb][c] + iv * gv;
            clds[pb][c] = cc;
            cv[jj] = cc;
            hv[jj] = ov * tanhf(cc);
        }

        // publish h_{ts+1}: one 4B write-through relaxed atomic store (2 bf16)
        union { ushort u2[2]; uint u; } hsv;
        hsv.u2[0] = f2bf(hv[0]);
        hsv.u2[1] = f2bf(hv[1]);
        ushort* hnext = ((ts + 1) & 1) ? h1buf : h0buf;
        __hip_atomic_store((uint*)(hnext + (size_t)pb * H_ + bid * 8 + pc),
                           hsv.u, __ATOMIC_RELAXED, __HIP_MEMORY_SCOPE_AGENT);

        // 8. order: own stores (incl. DMA) complete -> all threads done -> signal
        asm volatile("s_waitcnt vmcnt(0)" ::: "memory");
        __syncthreads();
        if (tid == 0)
            __hip_atomic_store(&flags[bid], ts + 1, __ATOMIC_RELAXED,
                               __HIP_MEMORY_SCOPE_AGENT);

        // 9. deferred (off critical path): hidden_seq / final h_t,c_t stores
        f32x2 hq = {hv[0], hv[1]};
        *(f32x2*)(out + ((size_t)pb * S_ + ts) * H_ + bid * 8 + pc) = hq;
        if (ts == S_ - 1) {
            f32x2 cq = {cv[0], cv[1]};
            size_t tail = (size_t)B_ * S_ * H_;
            *(f32x2*)(out + tail + (size_t)pb * H_ + bid * 8 + pc) = hq;
            *(f32x2*)(out + tail + (size_t)B_ * H_ + (size_t)pb * H_ + bid * 8 + pc) = cq;
        }
    }

    // persist cell state (graph-replay safe: init_all re-zeros each run)
    __syncthreads();
    cg[(size_t)pb * H_ + bid * 8 + pc]     = clds[pb][pc];
    cg[(size_t)pb * H_ + bid * 8 + pc + 1] = clds[pb][pc + 1];
}

extern "C" void kernel_launch(void* const* d_in, const int* in_sizes, int n_in,
                              void* d_out, int out_size, void* d_ws, size_t ws_size,
                              hipStream_t stream) {
    const float* x    = (const float*)d_in[0];
    const float* W    = (const float*)d_in[1];
    const float* U    = (const float*)d_in[2];
    const float* bias = (const float*)d_in[3];
    float* out = (float*)d_out;
    char* ws = (char*)d_ws;

    // ws layout: WUt 4MiB | h0 64K | h1 64K | c 128K | flags 4K | xbf 64MiB
    ushort* WUt = (ushort*)ws;
    size_t off = (size_t)4 * 1024 * 1024;
    ushort* h0 = (ushort*)(ws + off); off += (size_t)B_ * H_ * sizeof(ushort);
    ushort* h1 = (ushort*)(ws + off); off += (size_t)B_ * H_ * sizeof(ushort);
    float*  cg = (float*)(ws + off);  off += (size_t)B_ * H_ * sizeof(float);
    int* flags = (int*)(ws + off);    off += 4096;
    ushort* xbf = (ushort*)(ws + off);
    size_t need = off + (size_t)B_ * S_ * I_ * sizeof(ushort);   // ~68.3 MiB
    bool use_xbf = (ws_size >= need);

    prep_wut<<<dim3(G4 / 32, KTOT / 32), dim3(32, 32), 0, stream>>>(W, U, WUt);
    init_all<<<(B_ * H_) / 256, 256, 0, stream>>>(h0, h1, cg, flags);

    if (use_xbf) {
        prep_xbf<<<4096, 256, 0, stream>>>(x, xbf);
        lstm_persist<true><<<dim3(NBLK), 256, 0, stream>>>(
            x, xbf, WUt, bias, h0, h1, cg, flags, out);
    } else {
        lstm_persist<false><<<dim3(NBLK), 256, 0, stream>>>(
            x, xbf, WUt, bias, h0, h1, cg, flags, out);
    }
}

// Round 11
// 11984.795 us; speedup vs baseline: 2.5579x; 1.0243x over previous
//
#include <hip/hip_runtime.h>
#include <hip/hip_bf16.h>

#define B_   64
#define S_   1024
#define I_   512
#define H_   512
#define G4   2048   // 4*H
#define KTOT 1024   // I_ + H_
#define NBLK 64     // persistent grid (<< 256 CUs -> co-resident)
#define FSTR 32     // flag stride in ints: one flag per 128B cache line

typedef float f32x4 __attribute__((ext_vector_type(4)));
typedef float f32x2 __attribute__((ext_vector_type(2)));
typedef short s16x8 __attribute__((ext_vector_type(8)));

#define ULD_PITCH 520   // 512 data shorts + 8 pad

__device__ inline ushort f2bf(float f) {
    union { __hip_bfloat16 h; ushort u; } v;
    v.h = __float2bfloat16(f);
    return v.u;
}

__device__ inline s16x8 cvt_frag(const float* p) {
    float4 a = *(const float4*)p;
    float4 b = *(const float4*)(p + 4);
    s16x8 r;
    r[0] = (short)f2bf(a.x); r[1] = (short)f2bf(a.y);
    r[2] = (short)f2bf(a.z); r[3] = (short)f2bf(a.w);
    r[4] = (short)f2bf(b.x); r[5] = (short)f2bf(b.y);
    r[6] = (short)f2bf(b.z); r[7] = (short)f2bf(b.w);
    return r;
}

// Coherent (agent-scope, cache-bypassing) 16B h-frag load as 2x8B relaxed atomics.
__device__ inline s16x8 ld_h16(const ushort* p) {
    union { unsigned long long u[2]; s16x8 v; } r;
    const unsigned long long* q = (const unsigned long long*)p;
    r.u[0] = __hip_atomic_load(q,     __ATOMIC_RELAXED, __HIP_MEMORY_SCOPE_AGENT);
    r.u[1] = __hip_atomic_load(q + 1, __ATOMIC_RELAXED, __HIP_MEMORY_SCOPE_AGENT);
    return r.v;
}

// Async global->LDS DMA, 16B per lane. LDS dest = wave-uniform base + lane*16
// (HW rule); global src is per-lane. Tracked by the issuing wave's vmcnt.
__device__ inline void dma16(const ushort* g, ushort* l) {
    __builtin_amdgcn_global_load_lds(
        (const __attribute__((address_space(1))) void*)g,
        (__attribute__((address_space(3))) void*)l,
        16, 0, 0);
}

// WUt[g][k] = (k<512 ? W[k][g] : U[k-512][g]) as bf16.  [2048][1024]
__global__ __launch_bounds__(1024) void prep_wut(const float* __restrict__ W,
                                                 const float* __restrict__ U,
                                                 ushort* __restrict__ WUt) {
    __shared__ ushort lds[32][33];
    int g0 = blockIdx.x * 32, k0 = blockIdx.y * 32;
    int tx = threadIdx.x, ty = threadIdx.y;
    int k = k0 + ty, g = g0 + tx;
    float v = (k < I_) ? W[(size_t)k * G4 + g] : U[(size_t)(k - I_) * G4 + g];
    lds[ty][tx] = f2bf(v);
    __syncthreads();
    WUt[(size_t)(g0 + ty) * KTOT + k0 + tx] = lds[tx][ty];
}

// xbf = bf16(x), same [B][S][I] layout. One-time full-BW convert.
__global__ __launch_bounds__(256) void prep_xbf(const float* __restrict__ x,
                                                ushort* __restrict__ xbf) {
    size_t stride = (size_t)gridDim.x * 256 * 8;
    size_t total = (size_t)B_ * S_ * I_;
    for (size_t i = ((size_t)blockIdx.x * 256 + threadIdx.x) * 8; i < total; i += stride)
        *(s16x8*)(xbf + i) = cvt_frag(x + i);
}

__global__ __launch_bounds__(256) void init_all(ushort* __restrict__ h0,
                                                ushort* __restrict__ h1,
                                                float* __restrict__ cg,
                                                int* __restrict__ flags) {
    int i = blockIdx.x * 256 + threadIdx.x;   // 32768 total
    h0[i] = 0;
    h1[i] = 0;
    cg[i] = 0.0f;
    if (i < NBLK * FSTR) flags[i] = 0;
}

// Persistent recurrent kernel: 64 blocks; block bid owns hidden cols
// [bid*8,+8) for all 4 gates (32 local gate-cols), all 64 batch rows.
// Protocol identical to the passing R8 kernel; ONE mechanism change:
// flags spread one-per-128B-line (FSTR) + slower poll, eliminating LLC
// hot-line contention that queued all critical-path coherent ops
// (h loads/stores, flag store) behind ~4096 pollers on 2 lines.
template <bool XBF>
__global__ __launch_bounds__(256, 1) void lstm_persist(
    const float* __restrict__ x, const ushort* __restrict__ xbf,
    const ushort* __restrict__ WUt, const float* __restrict__ bias,
    ushort* __restrict__ h0buf, ushort* __restrict__ h1buf,
    float* __restrict__ cg, int* __restrict__ flags,
    float* __restrict__ out)
{
    __shared__ ushort xs[64 * 512];           // 64 KB x-stage: inst i -> [i*512, +512)
    __shared__ ushort ulds[32 * ULD_PITCH];   // U slice [32 gcol][512+8]  (~32.5 KB)
    __shared__ float glt[32][68];             // [gcol][batch] gate staging
    __shared__ float clds[64][9];             // cell state, block-resident

    int bid = blockIdx.x;
    int tid = threadIdx.x;
    int wid = tid >> 6, lane = tid & 63;
    int wr = wid >> 1, wc = wid & 1;          // wave: rows [wr*32,+32) x gcols [wc*16,+16)
    int m = lane & 15, q = lane >> 4;
    int lg = wc * 16 + m;                     // lane's local gate-col
    int r0 = wr * 32 + m, r1 = r0 + 16;       // lane's two batch rows

    // per-lane W row pointer (W part of WUt, k in [0,512))
    const ushort* wp = WUt + (size_t)((lg >> 3) * H_ + bid * 8 + (lg & 7)) * KTOT + q * 8;

    // stage U slice into LDS once
    {
        int r = tid >> 3, seg = tid & 7;
        const ushort* src = WUt + (size_t)((r >> 3) * H_ + bid * 8 + (r & 7)) * KTOT + 512 + seg * 64;
        ushort* dst = ulds + r * ULD_PITCH + seg * 64;
        #pragma unroll
        for (int i = 0; i < 8; ++i)
            *(s16x8*)(dst + i * 8) = *(const s16x8*)(src + i * 8);
    }
    const ushort* up = ulds + lg * ULD_PITCH + q * 8;

    // pointwise role: thread -> (batch pb, cols pc, pc+1)
    int pb = tid >> 2, pc = (tid & 3) * 2;
    clds[pb][pc]     = cg[(size_t)pb * H_ + bid * 8 + pc];
    clds[pb][pc + 1] = cg[(size_t)pb * H_ + bid * 8 + pc + 1];
    float bg_[4][2];
    #pragma unroll
    for (int g = 0; g < 4; ++g) {
        bg_[g][0] = bias[g * H_ + bid * 8 + pc];
        bg_[g][1] = bias[g * H_ + bid * 8 + pc + 1];
    }

    // x DMA: inst (g,kk) for wave-group wr covers rows wr*32+g*16+[0..15],
    // row-bytes [kk*64, +64). Lane l supplies row (l&15), 16B segment (l>>4).
    // Only wc==0 waves issue (wc==1 waves read the same LDS afterwards).
    if constexpr (XBF) {
        if (wc == 0) {
            #pragma unroll
            for (int g = 0; g < 2; ++g) {
                const ushort* grow = xbf + (size_t)(wr * 32 + g * 16 + m) * S_ * I_ + q * 8;
                #pragma unroll
                for (int kk = 0; kk < 16; ++kk)
                    dma16(grow + kk * 32, &xs[(wr * 32 + g * 16 + kk) * 512]);
            }
        }
    }
    asm volatile("s_waitcnt vmcnt(0)" ::: "memory");
    __syncthreads();

    // per-lane f32 x bases (fallback path)
    const float* xf0 = x + (size_t)r0 * S_ * I_ + q * 8;
    const float* xf1 = x + (size_t)r1 * S_ * I_ + q * 8;

    int budget = 1 << 21;   // bounded spin: wedge -> ~0.1s termination, no GPU hang

    for (int ts = 0; ts < S_; ++ts) {
        // 1. x@W from LDS-staged frags (linear lane*16 addressing, conflict-free)
        f32x4 acc0 = {0.f, 0.f, 0.f, 0.f};
        f32x4 acc1 = {0.f, 0.f, 0.f, 0.f};
        if constexpr (XBF) {
            #pragma unroll
            for (int kk = 0; kk < 16; ++kk) {
                s16x8 A0 = *(const s16x8*)&xs[(wr * 32 + kk) * 512 + lane * 8];
                s16x8 A1 = *(const s16x8*)&xs[(wr * 32 + 16 + kk) * 512 + lane * 8];
                s16x8 Bw = *(const s16x8*)(wp + kk * 32);
                acc0 = __builtin_amdgcn_mfma_f32_16x16x32_bf16(A0, Bw, acc0, 0, 0, 0);
                acc1 = __builtin_amdgcn_mfma_f32_16x16x32_bf16(A1, Bw, acc1, 0, 0, 0);
            }
        } else {
            const float* xa = xf0 + (size_t)ts * I_;
            const float* xb = xf1 + (size_t)ts * I_;
            #pragma unroll
            for (int kk = 0; kk < 16; ++kk) {
                s16x8 A0 = cvt_frag(xa + kk * 32);
                s16x8 A1 = cvt_frag(xb + kk * 32);
                s16x8 Bw = *(const s16x8*)(wp + kk * 32);
                acc0 = __builtin_amdgcn_mfma_f32_16x16x32_bf16(A0, Bw, acc0, 0, 0, 0);
                acc1 = __builtin_amdgcn_mfma_f32_16x16x32_bf16(A1, Bw, acc1, 0, 0, 0);
            }
        }

        // 2. wait until every block published h_ts (flag >= ts).
        //    One flag per 128B line; moderated poll rate keeps LLC pressure low.
        if (tid < NBLK) {
            while (budget > 0 &&
                   __hip_atomic_load(&flags[tid * FSTR], __ATOMIC_RELAXED,
                                     __HIP_MEMORY_SCOPE_AGENT) < ts) {
                __builtin_amdgcn_s_sleep(2);
                --budget;
            }
        }
        __syncthreads();   // also orders phase-1 LDS reads before this step's DMA

        // 3. burst-issue all coherent h loads (critical path)
        const ushort* hrow = (ts & 1) ? h1buf : h0buf;
        const ushort* ha0 = hrow + (size_t)r0 * H_ + q * 8;
        const ushort* ha1 = hrow + (size_t)r1 * H_ + q * 8;
        s16x8 hfr[2][16];
        #pragma unroll
        for (int kk = 0; kk < 16; ++kk) {
            hfr[0][kk] = ld_h16(ha0 + kk * 32);
            hfr[1][kk] = ld_h16(ha1 + kk * 32);
        }

        // 4. issue x-DMA for ts+1 (completes under phases 5-8; drained at phase 8)
        if constexpr (XBF) {
            if (wc == 0) {
                int tn = (ts + 1) & (S_ - 1);
                #pragma unroll
                for (int g = 0; g < 2; ++g) {
                    const ushort* grow = xbf
                        + ((size_t)(wr * 32 + g * 16 + m) * S_ + tn) * I_ + q * 8;
                    #pragma unroll
                    for (int kk = 0; kk < 16; ++kk)
                        dma16(grow + kk * 32, &xs[(wr * 32 + g * 16 + kk) * 512]);
                }
            }
        }

        // 5. h @ U-slice (B from LDS)
        #pragma unroll
        for (int kk = 0; kk < 16; ++kk) {
            s16x8 Bu = *(const s16x8*)(up + kk * 32);
            acc0 = __builtin_amdgcn_mfma_f32_16x16x32_bf16(hfr[0][kk], Bu, acc0, 0, 0, 0);
            acc1 = __builtin_amdgcn_mfma_f32_16x16x32_bf16(hfr[1][kk], Bu, acc1, 0, 0, 0);
        }

        // 6. stage gates transposed: glt[gcol][batch]
        *(f32x4*)&glt[lg][wr * 32 + q * 4]      = acc0;
        *(f32x4*)&glt[lg][wr * 32 + 16 + q * 4] = acc1;
        __syncthreads();

        // 7. pointwise: gates -> c,h  (c stays in LDS)
        float hv[2], cv[2];
        #pragma unroll
        for (int jj = 0; jj < 2; ++jj) {
            int c = pc + jj;
            float gi = glt[c][pb]      + bg_[0][jj];
            float gf = glt[8 + c][pb]  + bg_[1][jj];
            float gg = glt[16 + c][pb] + bg_[2][jj];
            float go = glt[24 + c][pb] + bg_[3][jj];
            float iv = 1.f / (1.f + __expf(-gi));
            float fv = 1.f / (1.f + __expf(-gf));
            float gv = tanhf(gg);
            float ov = 1.f / (1.f + __expf(-go));
            float cc = fv * clds[pb][c] + iv * gv;
            clds[pb][c] = cc;
            cv[jj] = cc;
            hv[jj] = ov * tanhf(cc);
        }

        // publish h_{ts+1}: one 4B write-through relaxed atomic store (2 bf16)
        union { ushort u2[2]; uint u; } hsv;
        hsv.u2[0] = f2bf(hv[0]);
        hsv.u2[1] = f2bf(hv[1]);
        ushort* hnext = ((ts + 1) & 1) ? h1buf : h0buf;
        __hip_atomic_store((uint*)(hnext + (size_t)pb * H_ + bid * 8 + pc),
                           hsv.u, __ATOMIC_RELAXED, __HIP_MEMORY_SCOPE_AGENT);

        // 8. order: own stores (incl. DMA) complete -> all threads done -> signal
        asm volatile("s_waitcnt vmcnt(0)" ::: "memory");
        __syncthreads();
        if (tid == 0)
            __hip_atomic_store(&flags[bid * FSTR], ts + 1, __ATOMIC_RELAXED,
                               __HIP_MEMORY_SCOPE_AGENT);

        // 9. deferred (off critical path): hidden_seq / final h_t,c_t stores
        f32x2 hq = {hv[0], hv[1]};
        *(f32x2*)(out + ((size_t)pb * S_ + ts) * H_ + bid * 8 + pc) = hq;
        if (ts == S_ - 1) {
            f32x2 cq = {cv[0], cv[1]};
            size_t tail = (size_t)B_ * S_ * H_;
            *(f32x2*)(out + tail + (size_t)pb * H_ + bid * 8 + pc) = hq;
            *(f32x2*)(out + tail + (size_t)B_ * H_ + (size_t)pb * H_ + bid * 8 + pc) = cq;
        }
    }

    // persist cell state (graph-replay safe: init_all re-zeros each run)
    __syncthreads();
    cg[(size_t)pb * H_ + bid * 8 + pc]     = clds[pb][pc];
    cg[(size_t)pb * H_ + bid * 8 + pc + 1] = clds[pb][pc + 1];
}

extern "C" void kernel_launch(void* const* d_in, const int* in_sizes, int n_in,
                              void* d_out, int out_size, void* d_ws, size_t ws_size,
                              hipStream_t stream) {
    const float* x    = (const float*)d_in[0];
    const float* W    = (const float*)d_in[1];
    const float* U    = (const float*)d_in[2];
    const float* bias = (const float*)d_in[3];
    float* out = (float*)d_out;
    char* ws = (char*)d_ws;

    // ws layout: WUt 4MiB | h0 64K | h1 64K | c 128K | flags 8K | xbf 64MiB
    ushort* WUt = (ushort*)ws;
    size_t off = (size_t)4 * 1024 * 1024;
    ushort* h0 = (ushort*)(ws + off); off += (size_t)B_ * H_ * sizeof(ushort);
    ushort* h1 = (ushort*)(ws + off); off += (size_t)B_ * H_ * sizeof(ushort);
    float*  cg = (float*)(ws + off);  off += (size_t)B_ * H_ * sizeof(float);
    int* flags = (int*)(ws + off);    off += (size_t)NBLK * FSTR * sizeof(int);
    ushort* xbf = (ushort*)(ws + off);
    size_t need = off + (size_t)B_ * S_ * I_ * sizeof(ushort);   // ~68.3 MiB
    bool use_xbf = (ws_size >= need);

    prep_wut<<<dim3(G4 / 32, KTOT / 32), dim3(32, 32), 0, stream>>>(W, U, WUt);
    init_all<<<(B_ * H_) / 256, 256, 0, stream>>>(h0, h1, cg, flags);

    if (use_xbf) {
        prep_xbf<<<4096, 256, 0, stream>>>(x, xbf);
        lstm_persist<true><<<dim3(NBLK), 256, 0, stream>>>(
            x, xbf, WUt, bias, h0, h1, cg, flags, out);
    } else {
        lstm_persist<false><<<dim3(NBLK), 256, 0, stream>>>(
            x, xbf, WUt, bias, h0, h1, cg, flags, out);
    }
}

// Round 12
// 8021.185 us; speedup vs baseline: 3.8218x; 1.4941x over previous
//
#include <hip/hip_runtime.h>
#include <hip/hip_bf16.h>

#define B_   64
#define S_   1024
#define I_   512
#define H_   512
#define G4   2048   // 4*H
#define KTOT 1024   // I_ + H_
#define NBLK 64     // persistent grid (<< 256 CUs -> co-resident)
#define FSTR 32     // flag stride in ints: one flag per 128B cache line

typedef float f32x4 __attribute__((ext_vector_type(4)));
typedef float f32x2 __attribute__((ext_vector_type(2)));
typedef short s16x8 __attribute__((ext_vector_type(8)));

#define ULD_PITCH 520   // 512 data shorts + 8 pad

__device__ inline ushort f2bf(float f) {
    union { __hip_bfloat16 h; ushort u; } v;
    v.h = __float2bfloat16(f);
    return v.u;
}

__device__ inline s16x8 cvt_frag(const float* p) {
    float4 a = *(const float4*)p;
    float4 b = *(const float4*)(p + 4);
    s16x8 r;
    r[0] = (short)f2bf(a.x); r[1] = (short)f2bf(a.y);
    r[2] = (short)f2bf(a.z); r[3] = (short)f2bf(a.w);
    r[4] = (short)f2bf(b.x); r[5] = (short)f2bf(b.y);
    r[6] = (short)f2bf(b.z); r[7] = (short)f2bf(b.w);
    return r;
}

// Coherent 16B load: NORMAL (coalescing) vector load with sc0+sc1 -> bypasses
// L1/L2, served at the LLC coherence point where write-through publishes land.
// Replaces 2x8B atomic loads, which do NOT coalesce (64 discrete transactions
// per instruction -> ~16K transactions/block/step was the measured ~12us floor).
__device__ inline s16x8 ldg16_coh(const ushort* p) {
    s16x8 r;
    asm volatile("global_load_dwordx4 %0, %1, off sc0 sc1"
                 : "=v"(r) : "v"(p));
    return r;
}

// Async global->LDS DMA, 16B per lane. LDS dest = wave-uniform base + lane*16
// (HW rule); global src is per-lane. Tracked by the issuing wave's vmcnt.
__device__ inline void dma16(const ushort* g, ushort* l) {
    __builtin_amdgcn_global_load_lds(
        (const __attribute__((address_space(1))) void*)g,
        (__attribute__((address_space(3))) void*)l,
        16, 0, 0);
}

// WUt[g][k] = (k<512 ? W[k][g] : U[k-512][g]) as bf16.  [2048][1024]
__global__ __launch_bounds__(1024) void prep_wut(const float* __restrict__ W,
                                                 const float* __restrict__ U,
                                                 ushort* __restrict__ WUt) {
    __shared__ ushort lds[32][33];
    int g0 = blockIdx.x * 32, k0 = blockIdx.y * 32;
    int tx = threadIdx.x, ty = threadIdx.y;
    int k = k0 + ty, g = g0 + tx;
    float v = (k < I_) ? W[(size_t)k * G4 + g] : U[(size_t)(k - I_) * G4 + g];
    lds[ty][tx] = f2bf(v);
    __syncthreads();
    WUt[(size_t)(g0 + ty) * KTOT + k0 + tx] = lds[tx][ty];
}

// xbf = bf16(x), same [B][S][I] layout. One-time full-BW convert.
__global__ __launch_bounds__(256) void prep_xbf(const float* __restrict__ x,
                                                ushort* __restrict__ xbf) {
    size_t stride = (size_t)gridDim.x * 256 * 8;
    size_t total = (size_t)B_ * S_ * I_;
    for (size_t i = ((size_t)blockIdx.x * 256 + threadIdx.x) * 8; i < total; i += stride)
        *(s16x8*)(xbf + i) = cvt_frag(x + i);
}

__global__ __launch_bounds__(256) void init_all(ushort* __restrict__ h0,
                                                ushort* __restrict__ h1,
                                                float* __restrict__ cg,
                                                int* __restrict__ flags) {
    int i = blockIdx.x * 256 + threadIdx.x;   // 32768 total
    h0[i] = 0;
    h1[i] = 0;
    cg[i] = 0.0f;
    if (i < NBLK * FSTR) flags[i] = 0;
}

// Persistent recurrent kernel: 64 blocks; block bid owns hidden cols
// [bid*8,+8) for all 4 gates (32 local gate-cols), all 64 batch rows.
// Protocol identical to the passing R11 kernel; ONE mechanism change:
// coherent h reads via coalescing sc0|sc1 dwordx4 loads instead of
// non-coalescing 8B atomics (16K -> ~2K LLC transactions per block/step).
template <bool XBF>
__global__ __launch_bounds__(256, 1) void lstm_persist(
    const float* __restrict__ x, const ushort* __restrict__ xbf,
    const ushort* __restrict__ WUt, const float* __restrict__ bias,
    ushort* __restrict__ h0buf, ushort* __restrict__ h1buf,
    float* __restrict__ cg, int* __restrict__ flags,
    float* __restrict__ out)
{
    __shared__ ushort xs[64 * 512];           // 64 KB x-stage: inst i -> [i*512, +512)
    __shared__ ushort ulds[32 * ULD_PITCH];   // U slice [32 gcol][512+8]  (~32.5 KB)
    __shared__ float glt[32][68];             // [gcol][batch] gate staging
    __shared__ float clds[64][9];             // cell state, block-resident

    int bid = blockIdx.x;
    int tid = threadIdx.x;
    int wid = tid >> 6, lane = tid & 63;
    int wr = wid >> 1, wc = wid & 1;          // wave: rows [wr*32,+32) x gcols [wc*16,+16)
    int m = lane & 15, q = lane >> 4;
    int lg = wc * 16 + m;                     // lane's local gate-col
    int r0 = wr * 32 + m, r1 = r0 + 16;       // lane's two batch rows

    // per-lane W row pointer (W part of WUt, k in [0,512))
    const ushort* wp = WUt + (size_t)((lg >> 3) * H_ + bid * 8 + (lg & 7)) * KTOT + q * 8;

    // stage U slice into LDS once
    {
        int r = tid >> 3, seg = tid & 7;
        const ushort* src = WUt + (size_t)((r >> 3) * H_ + bid * 8 + (r & 7)) * KTOT + 512 + seg * 64;
        ushort* dst = ulds + r * ULD_PITCH + seg * 64;
        #pragma unroll
        for (int i = 0; i < 8; ++i)
            *(s16x8*)(dst + i * 8) = *(const s16x8*)(src + i * 8);
    }
    const ushort* up = ulds + lg * ULD_PITCH + q * 8;

    // pointwise role: thread -> (batch pb, cols pc, pc+1)
    int pb = tid >> 2, pc = (tid & 3) * 2;
    clds[pb][pc]     = cg[(size_t)pb * H_ + bid * 8 + pc];
    clds[pb][pc + 1] = cg[(size_t)pb * H_ + bid * 8 + pc + 1];
    float bg_[4][2];
    #pragma unroll
    for (int g = 0; g < 4; ++g) {
        bg_[g][0] = bias[g * H_ + bid * 8 + pc];
        bg_[g][1] = bias[g * H_ + bid * 8 + pc + 1];
    }

    // x DMA: inst (g,kk) for wave-group wr covers rows wr*32+g*16+[0..15],
    // row-bytes [kk*64, +64). Lane l supplies row (l&15), 16B segment (l>>4).
    // Only wc==0 waves issue (wc==1 waves read the same LDS afterwards).
    if constexpr (XBF) {
        if (wc == 0) {
            #pragma unroll
            for (int g = 0; g < 2; ++g) {
                const ushort* grow = xbf + (size_t)(wr * 32 + g * 16 + m) * S_ * I_ + q * 8;
                #pragma unroll
                for (int kk = 0; kk < 16; ++kk)
                    dma16(grow + kk * 32, &xs[(wr * 32 + g * 16 + kk) * 512]);
            }
        }
    }
    asm volatile("s_waitcnt vmcnt(0)" ::: "memory");
    __syncthreads();

    // per-lane f32 x bases (fallback path)
    const float* xf0 = x + (size_t)r0 * S_ * I_ + q * 8;
    const float* xf1 = x + (size_t)r1 * S_ * I_ + q * 8;

    int budget = 1 << 21;   // bounded spin: wedge -> ~0.1s termination, no GPU hang

    for (int ts = 0; ts < S_; ++ts) {
        // 1. x@W from LDS-staged frags (linear lane*16 addressing, conflict-free)
        f32x4 acc0 = {0.f, 0.f, 0.f, 0.f};
        f32x4 acc1 = {0.f, 0.f, 0.f, 0.f};
        if constexpr (XBF) {
            #pragma unroll
            for (int kk = 0; kk < 16; ++kk) {
                s16x8 A0 = *(const s16x8*)&xs[(wr * 32 + kk) * 512 + lane * 8];
                s16x8 A1 = *(const s16x8*)&xs[(wr * 32 + 16 + kk) * 512 + lane * 8];
                s16x8 Bw = *(const s16x8*)(wp + kk * 32);
                acc0 = __builtin_amdgcn_mfma_f32_16x16x32_bf16(A0, Bw, acc0, 0, 0, 0);
                acc1 = __builtin_amdgcn_mfma_f32_16x16x32_bf16(A1, Bw, acc1, 0, 0, 0);
            }
        } else {
            const float* xa = xf0 + (size_t)ts * I_;
            const float* xb = xf1 + (size_t)ts * I_;
            #pragma unroll
            for (int kk = 0; kk < 16; ++kk) {
                s16x8 A0 = cvt_frag(xa + kk * 32);
                s16x8 A1 = cvt_frag(xb + kk * 32);
                s16x8 Bw = *(const s16x8*)(wp + kk * 32);
                acc0 = __builtin_amdgcn_mfma_f32_16x16x32_bf16(A0, Bw, acc0, 0, 0, 0);
                acc1 = __builtin_amdgcn_mfma_f32_16x16x32_bf16(A1, Bw, acc1, 0, 0, 0);
            }
        }

        // 2. wait until every block published h_ts (flag >= ts).
        if (tid < NBLK) {
            while (budget > 0 &&
                   __hip_atomic_load(&flags[tid * FSTR], __ATOMIC_RELAXED,
                                     __HIP_MEMORY_SCOPE_AGENT) < ts) {
                __builtin_amdgcn_s_sleep(2);
                --budget;
            }
        }
        __syncthreads();   // also orders phase-1 LDS reads before this step's DMA

        // 3. burst-issue all coherent h loads (coalescing dwordx4, sc0|sc1),
        //    then wait them (x-DMA for ts+1 is issued AFTER, so not drained here)
        const ushort* hrow = (ts & 1) ? h1buf : h0buf;
        const ushort* ha0 = hrow + (size_t)r0 * H_ + q * 8;
        const ushort* ha1 = hrow + (size_t)r1 * H_ + q * 8;
        s16x8 hfr[2][16];
        #pragma unroll
        for (int kk = 0; kk < 16; ++kk) {
            hfr[0][kk] = ldg16_coh(ha0 + kk * 32);
            hfr[1][kk] = ldg16_coh(ha1 + kk * 32);
        }
        asm volatile("s_waitcnt vmcnt(0)" ::: "memory");
        __builtin_amdgcn_sched_barrier(0);   // rule #18: pin consumers below the wait

        // 4. issue x-DMA for ts+1 (completes under phases 5-8; drained at phase 8)
        if constexpr (XBF) {
            if (wc == 0) {
                int tn = (ts + 1) & (S_ - 1);
                #pragma unroll
                for (int g = 0; g < 2; ++g) {
                    const ushort* grow = xbf
                        + ((size_t)(wr * 32 + g * 16 + m) * S_ + tn) * I_ + q * 8;
                    #pragma unroll
                    for (int kk = 0; kk < 16; ++kk)
                        dma16(grow + kk * 32, &xs[(wr * 32 + g * 16 + kk) * 512]);
                }
            }
        }

        // 5. h @ U-slice (B from LDS)
        #pragma unroll
        for (int kk = 0; kk < 16; ++kk) {
            s16x8 Bu = *(const s16x8*)(up + kk * 32);
            acc0 = __builtin_amdgcn_mfma_f32_16x16x32_bf16(hfr[0][kk], Bu, acc0, 0, 0, 0);
            acc1 = __builtin_amdgcn_mfma_f32_16x16x32_bf16(hfr[1][kk], Bu, acc1, 0, 0, 0);
        }

        // 6. stage gates transposed: glt[gcol][batch]
        *(f32x4*)&glt[lg][wr * 32 + q * 4]      = acc0;
        *(f32x4*)&glt[lg][wr * 32 + 16 + q * 4] = acc1;
        __syncthreads();

        // 7. pointwise: gates -> c,h  (c stays in LDS)
        float hv[2], cv[2];
        #pragma unroll
        for (int jj = 0; jj < 2; ++jj) {
            int c = pc + jj;
            float gi = glt[c][pb]      + bg_[0][jj];
            float gf = glt[8 + c][pb]  + bg_[1][jj];
            float gg = glt[16 + c][pb] + bg_[2][jj];
            float go = glt[24 + c][pb] + bg_[3][jj];
            float iv = 1.f / (1.f + __expf(-gi));
            float fv = 1.f / (1.f + __expf(-gf));
            float gv = tanhf(gg);
            float ov = 1.f / (1.f + __expf(-go));
            float cc = fv * clds[pb][c] + iv * gv;
            clds[pb][c] = cc;
            cv[jj] = cc;
            hv[jj] = ov * tanhf(cc);
        }

        // publish h_{ts+1}: one 4B write-through relaxed atomic store (2 bf16)
        union { ushort u2[2]; uint u; } hsv;
        hsv.u2[0] = f2bf(hv[0]);
        hsv.u2[1] = f2bf(hv[1]);
        ushort* hnext = ((ts + 1) & 1) ? h1buf : h0buf;
        __hip_atomic_store((uint*)(hnext + (size_t)pb * H_ + bid * 8 + pc),
                           hsv.u, __ATOMIC_RELAXED, __HIP_MEMORY_SCOPE_AGENT);

        // 8. order: own stores (incl. DMA) complete -> all threads done -> signal
        asm volatile("s_waitcnt vmcnt(0)" ::: "memory");
        __syncthreads();
        if (tid == 0)
            __hip_atomic_store(&flags[bid * FSTR], ts + 1, __ATOMIC_RELAXED,
                               __HIP_MEMORY_SCOPE_AGENT);

        // 9. deferred (off critical path): hidden_seq / final h_t,c_t stores
        f32x2 hq = {hv[0], hv[1]};
        *(f32x2*)(out + ((size_t)pb * S_ + ts) * H_ + bid * 8 + pc) = hq;
        if (ts == S_ - 1) {
            f32x2 cq = {cv[0], cv[1]};
            size_t tail = (size_t)B_ * S_ * H_;
            *(f32x2*)(out + tail + (size_t)pb * H_ + bid * 8 + pc) = hq;
            *(f32x2*)(out + tail + (size_t)B_ * H_ + (size_t)pb * H_ + bid * 8 + pc) = cq;
        }
    }

    // persist cell state (graph-replay safe: init_all re-zeros each run)
    __syncthreads();
    cg[(size_t)pb * H_ + bid * 8 + pc]     = clds[pb][pc];
    cg[(size_t)pb * H_ + bid * 8 + pc + 1] = clds[pb][pc + 1];
}

extern "C" void kernel_launch(void* const* d_in, const int* in_sizes, int n_in,
                              void* d_out, int out_size, void* d_ws, size_t ws_size,
                              hipStream_t stream) {
    const float* x    = (const float*)d_in[0];
    const float* W    = (const float*)d_in[1];
    const float* U    = (const float*)d_in[2];
    const float* bias = (const float*)d_in[3];
    float* out = (float*)d_out;
    char* ws = (char*)d_ws;

    // ws layout: WUt 4MiB | h0 64K | h1 64K | c 128K | flags 8K | xbf 64MiB
    ushort* WUt = (ushort*)ws;
    size_t off = (size_t)4 * 1024 * 1024;
    ushort* h0 = (ushort*)(ws + off); off += (size_t)B_ * H_ * sizeof(ushort);
    ushort* h1 = (ushort*)(ws + off); off += (size_t)B_ * H_ * sizeof(ushort);
    float*  cg = (float*)(ws + off);  off += (size_t)B_ * H_ * sizeof(float);
    int* flags = (int*)(ws + off);    off += (size_t)NBLK * FSTR * sizeof(int);
    ushort* xbf = (ushort*)(ws + off);
    size_t need = off + (size_t)B_ * S_ * I_ * sizeof(ushort);   // ~68.3 MiB
    bool use_xbf = (ws_size >= need);

    prep_wut<<<dim3(G4 / 32, KTOT / 32), dim3(32, 32), 0, stream>>>(W, U, WUt);
    init_all<<<(B_ * H_) / 256, 256, 0, stream>>>(h0, h1, cg, flags);

    if (use_xbf) {
        prep_xbf<<<4096, 256, 0, stream>>>(x, xbf);
        lstm_persist<true><<<dim3(NBLK), 256, 0, stream>>>(
            x, xbf, WUt, bias, h0, h1, cg, flags, out);
    } else {
        lstm_persist<false><<<dim3(NBLK), 256, 0, stream>>>(
            x, xbf, WUt, bias, h0, h1, cg, flags, out);
    }
}